// Round 1
// baseline (1150.974 us; speedup 1.0000x reference)
//
#include <hip/hip_runtime.h>

// StructureModule (IPA), B=1, N=768. Harness dtype ambiguous (bf16 vs fp32):
// a detect kernel sniffs s[] bit patterns and all kernels branch on the flag.
// dims: C_S=384, C_Z=128, C_H=16, H=12, PQ=4, PV=8, CO=2112
// (rocprof: FETCH ~305MB = one fp32 z pass -> runtime dtype is fp32; both paths kept.)

typedef unsigned short ushort_t;

__device__ __forceinline__ float bfr(ushort_t u) {
  return __uint_as_float(((unsigned int)u) << 16);
}
__device__ __forceinline__ ushort_t f2bf(float f) {
  unsigned int u = __float_as_uint(f);
  u += 0x7FFFu + ((u >> 16) & 1u);
  return (ushort_t)(u >> 16);
}

template<bool BF16>
__device__ __forceinline__ float ld(const void* p, size_t i) {
  if constexpr (BF16) return bfr(((const ushort_t*)p)[i]);
  else                return ((const float*)p)[i];
}
template<bool BF16>
__device__ __forceinline__ void ld4(const void* p, size_t i, float* o) {
  if constexpr (BF16) {
    uint2 u = *(const uint2*)((const ushort_t*)p + i);   // i multiple of 4
    o[0]=__uint_as_float(u.x<<16); o[1]=__uint_as_float(u.x & 0xffff0000u);
    o[2]=__uint_as_float(u.y<<16); o[3]=__uint_as_float(u.y & 0xffff0000u);
  } else {
    float4 v = *(const float4*)((const float*)p + i);
    o[0]=v.x; o[1]=v.y; o[2]=v.z; o[3]=v.w;
  }
}
template<bool BF16>
__device__ __forceinline__ void ld2(const void* p, size_t i, float& x, float& y) {
  if constexpr (BF16) {
    unsigned int u = *(const unsigned int*)((const ushort_t*)p + i);  // i even
    x = __uint_as_float(u << 16); y = __uint_as_float(u & 0xffff0000u);
  } else {
    float2 v = *(const float2*)((const float*)p + i);
    x = v.x; y = v.y;
  }
}
__device__ __forceinline__ void unp8(uint4 v, float* f) {
  f[0]=__uint_as_float(v.x<<16); f[1]=__uint_as_float(v.x&0xffff0000u);
  f[2]=__uint_as_float(v.y<<16); f[3]=__uint_as_float(v.y&0xffff0000u);
  f[4]=__uint_as_float(v.z<<16); f[5]=__uint_as_float(v.z&0xffff0000u);
  f[6]=__uint_as_float(v.w<<16); f[7]=__uint_as_float(v.w&0xffff0000u);
}
__device__ __forceinline__ void unp4(uint2 v, float* f) {
  f[0]=__uint_as_float(v.x<<16); f[1]=__uint_as_float(v.x&0xffff0000u);
  f[2]=__uint_as_float(v.y<<16); f[3]=__uint_as_float(v.y&0xffff0000u);
}
__device__ __forceinline__ float f4get(float4 v, int e) {   // e compile-time after unroll
  return e==0 ? v.x : (e==1 ? v.y : (e==2 ? v.z : v.w));
}

#define NT 768
#define ZROWE 98304   /* elements per z q-row: 768*128 */

// ---------------------------------------------------------------------------
// dtype sniffer: bf16 pairs -> bits[14:7] of each word are a N(0,1) exponent
// ---------------------------------------------------------------------------
__global__ void k_detect(const void* s, int* flag) {
  if (blockIdx.x == 0 && threadIdx.x == 0) {
    const unsigned int* w = (const unsigned int*)s;
    int cnt = 0;
    for (int i = 0; i < 256; ++i) {
      unsigned int e = (w[i] >> 7) & 0xFFu;
      cnt += (e >= 118u && e <= 131u) ? 1 : 0;
    }
    *flag = (cnt >= 128) ? 1 : 0;
  }
}

// ---------------------------------------------------------------------------
// Kernel 1: projections -> bf16 workspace
//   q  [n][192]           k  [n][h*16+c]      vT [c(192)][n]   (transposed!)
//   qp [n][144]           kp [n][h*12+p*3+i]  vpT[j(288)][n]   (transposed!)
// float4/uint2 weight loads, 4 outputs/thread (4 independent FMA chains).
// ---------------------------------------------------------------------------
struct ProjSmem {
  float sl[384];
  float pbuf[576];
  float Rl[9];
  float tl[3];
};

template<bool BF16>
__device__ void proj_body(ProjSmem& sm,
            const void* s, const void* R, const void* t,
            const void* Wq, const void* bq, const void* Wkv, const void* bkv,
            const void* Wqp, const void* bqp, const void* Wkvp, const void* bkvp,
            ushort_t* qo, ushort_t* ko, ushort_t* vTo,
            ushort_t* qpo, ushort_t* kpo, ushort_t* vpTo)
{
  const int n = blockIdx.x, tid = threadIdx.x;
  for (int i = tid; i < 96; i += 256) {
    float f[4]; ld4<BF16>(s, (size_t)n*384 + i*4, f);
    *(float4*)&sm.sl[i*4] = make_float4(f[0],f[1],f[2],f[3]);
  }
  if (tid >= 128 && tid < 137) sm.Rl[tid-128] = ld<BF16>(R, (size_t)n*9 + (tid-128));
  if (tid >= 160 && tid < 163) sm.tl[tid-160] = ld<BF16>(t, (size_t)n*3 + (tid-160));
  __syncthreads();

  for (int g = tid; g < 288; g += 256) {     // 288 quads of 4 output cols
    const void* W; const void* bias; int ldw, cj;
    if (g < 48)       { W=Wq;   bias=bq;   ldw=192; cj=g*4;       }
    else if (g < 144) { W=Wkv;  bias=bkv;  ldw=384; cj=g*4-192;   }
    else if (g < 180) { W=Wqp;  bias=bqp;  ldw=144; cj=g*4-576;   }
    else              { W=Wkvp; bias=bkvp; ldw=432; cj=g*4-720;   }
    float a0 = ld<BF16>(bias, cj+0), a1 = ld<BF16>(bias, cj+1),
          a2 = ld<BF16>(bias, cj+2), a3 = ld<BF16>(bias, cj+3);
    #pragma unroll 4
    for (int i = 0; i < 384; ++i) {
      float w[4]; ld4<BF16>(W, (size_t)i*ldw + cj, w);
      const float sv = sm.sl[i];
      a0 = fmaf(sv, w[0], a0); a1 = fmaf(sv, w[1], a1);
      a2 = fmaf(sv, w[2], a2); a3 = fmaf(sv, w[3], a3);
    }
    const int j = g*4;
    if (j < 192) {
      ushort_t* d = qo + (size_t)n*192 + j;
      d[0]=f2bf(a0); d[1]=f2bf(a1); d[2]=f2bf(a2); d[3]=f2bf(a3);
    } else if (j < 576) {
      const int c = j - 192, h = c >> 5, r = c & 31;   // quad stays in one half
      if (r < 16) {
        ushort_t* d = ko + (size_t)n*192 + h*16 + r;
        d[0]=f2bf(a0); d[1]=f2bf(a1); d[2]=f2bf(a2); d[3]=f2bf(a3);
      } else {
        const int cc = h*16 + (r-16);
        vTo[(size_t)(cc+0)*NT + n] = f2bf(a0);
        vTo[(size_t)(cc+1)*NT + n] = f2bf(a1);
        vTo[(size_t)(cc+2)*NT + n] = f2bf(a2);
        vTo[(size_t)(cc+3)*NT + n] = f2bf(a3);
      }
    } else {
      *(float4*)&sm.pbuf[j-576] = make_float4(a0,a1,a2,a3);
    }
  }
  __syncthreads();

  if (tid < 48) {   // q points: j -> (h=j/4, pq=j%4); store [n][j*3+i]
    const int j = tid;
    float lx = sm.pbuf[j], ly = sm.pbuf[48+j], lz = sm.pbuf[96+j];
    #pragma unroll
    for (int i = 0; i < 3; ++i) {
      float g = sm.Rl[i*3+0]*lx + sm.Rl[i*3+1]*ly + sm.Rl[i*3+2]*lz + sm.tl[i];
      qpo[(size_t)n*144 + j*3 + i] = f2bf(g);
    }
  } else if (tid >= 64 && tid < 208) {  // kv points
    const int j = tid - 64;
    float lx = sm.pbuf[144+j], ly = sm.pbuf[288+j], lz = sm.pbuf[432+j];
    const int h = j / 12, pp = j % 12;
    #pragma unroll
    for (int i = 0; i < 3; ++i) {
      float g = sm.Rl[i*3+0]*lx + sm.Rl[i*3+1]*ly + sm.Rl[i*3+2]*lz + sm.tl[i];
      if (pp < 4) kpo[(size_t)n*144 + h*12 + pp*3 + i]         = f2bf(g);
      else        vpTo[(size_t)(h*24 + (pp-4)*3 + i)*NT + n]   = f2bf(g);
    }
  }
}

__global__ __launch_bounds__(256)
void k_proj(const int* flag,
            const void* s, const void* R, const void* t,
            const void* Wq, const void* bq, const void* Wkv, const void* bkv,
            const void* Wqp, const void* bqp, const void* Wkvp, const void* bkvp,
            ushort_t* qo, ushort_t* ko, ushort_t* vTo,
            ushort_t* qpo, ushort_t* kpo, ushort_t* vpTo)
{
  __shared__ ProjSmem sm;
  if (*flag) proj_body<true >(sm, s,R,t,Wq,bq,Wkv,bkv,Wqp,bqp,Wkvp,bkvp,qo,ko,vTo,qpo,kpo,vpTo);
  else       proj_body<false>(sm, s,R,t,Wq,bq,Wkv,bkv,Wqp,bqp,Wkvp,bkvp,qo,ko,vTo,qpo,kpo,vpTo);
}

// ---------------------------------------------------------------------------
// Kernel 2: per-query-row attention; cat row scribbled into own (dead) z row.
// LDS union {phase-A: Wb,q,qp} / {phase-C: catrow,opt} -> 45.4KB -> 3 blk/CU.
// ---------------------------------------------------------------------------
struct __align__(16) AttnSmem {
  float probs[12 * NT];            // 36864 B, alive A..C
  union {
    struct {
      float4 Wbl[128*3];           // [c][h-quad]  6144 B
      float4 ql4[12*4];            // [h][16 floats] 768 B
      float4 qpl4[12*4];           // [h][12 used + 4 pad] 768 B
      float  hwc[12], bbl[12];     // 96 B
    } a;                            // 7776 B
    struct {
      float catrow[2112];          // 8448 B
      float opt[288];              // 1152 B
    } c;                            // 9600 B
  } u;
};  // 46464 B total -> 3 blocks/CU (3*46464 <= 163840)

template<bool BF16>
__device__ void attn_body(AttnSmem& sm,
            void* z, const void* Rg, const void* tg, const void* mg,
            const void* Wb, const void* bbp, const void* hwg,
            const ushort_t* qB, const ushort_t* kB, const ushort_t* vTB,
            const ushort_t* qpB, const ushort_t* kpB, const ushort_t* vpTB)
{
  const int qrow = blockIdx.x, tid = threadIdx.x;

  // ---- stage A-phase smem ----
  for (int i = tid; i < 128*12; i += 256) ((float*)sm.u.a.Wbl)[i] = ld<BF16>(Wb, i);
  if (tid < 48) {                       // q: 12h x 16, as float4s
    const int h = tid >> 2, part = tid & 3;
    float f[4];
    unp4(*(const uint2*)(qB + (size_t)qrow*192 + h*16 + part*4), f);
    sm.u.a.ql4[h*4+part] = make_float4(f[0],f[1],f[2],f[3]);
  } else if (tid >= 64 && tid < 112) {  // qp: 12h x 12 -> padded [h][16]
    const int j = tid - 64, h = j >> 2, part = j & 3;
    if (part < 3) {
      float f[4];
      unp4(*(const uint2*)(qpB + (size_t)qrow*144 + h*12 + part*4), f);
      sm.u.a.qpl4[h*4+part] = make_float4(f[0],f[1],f[2],f[3]);
    }
  } else if (tid >= 192 && tid < 204) {
    const int h = tid - 192;
    float x = ld<BF16>(hwg, h);
    float sp = (x > 20.f) ? x : log1pf(expf(x));     // softplus
    sm.u.a.hwc[h] = -0.5f * sp * 0.13608276348795434f;   // * sqrt(1/54), fold -0.5
    sm.u.a.bbl[h] = ld<BF16>(bbp, h);
  }
  __syncthreads();
  const float mq = ld<BF16>(mg, qrow);

  // ---- Phase A: logits. 3 kk-rows fused per thread: the 3 ds_read_b128 of
  // the Wb column are amortized over 3 rows (3x fewer LDS reads). ----
  {
    const int kk0 = tid;                       // kk0, +256, +512
    float accb[3][12];
    #pragma unroll
    for (int h = 0; h < 12; ++h) {
      const float b = sm.u.a.bbl[h];
      accb[0][h] = b; accb[1][h] = b; accb[2][h] = b;
    }
    const size_t zb = ((size_t)qrow*NT + kk0)*128;
    for (int c4 = 0; c4 < 32; ++c4) {
      float z0[4], z1[4], z2[4];
      ld4<BF16>(z, zb +           c4*4, z0);
      ld4<BF16>(z, zb + 256*128 + c4*4, z1);
      ld4<BF16>(z, zb + 512*128 + c4*4, z2);
      #pragma unroll
      for (int e = 0; e < 4; ++e) {
        const int c = c4*4 + e;
        float wr[12];
        *(float4*)&wr[0] = sm.u.a.Wbl[c*3+0];
        *(float4*)&wr[4] = sm.u.a.Wbl[c*3+1];
        *(float4*)&wr[8] = sm.u.a.Wbl[c*3+2];
        #pragma unroll
        for (int h = 0; h < 12; ++h) {
          accb[0][h] = fmaf(z0[e], wr[h], accb[0][h]);
          accb[1][h] = fmaf(z1[e], wr[h], accb[1][h]);
          accb[2][h] = fmaf(z2[e], wr[h], accb[2][h]);
        }
      }
    }
    #pragma unroll
    for (int r = 0; r < 3; ++r) {
      const int kk = kk0 + r*256;
      const uint4* kr  = (const uint4*)(kB  + (size_t)kk*192);  // 16B-aligned
      const uint2* kpr = (const uint2*)(kpB + (size_t)kk*144);  // 8B-aligned
      const float mk = ld<BF16>(mg, kk);
      const float maskterm = 100000.0f * (mq*mk - 1.0f);
      #pragma unroll
      for (int h = 0; h < 12; ++h) {
        float kf[16];
        unp8(kr[2*h+0], kf); unp8(kr[2*h+1], kf+8);
        float qf[16];
        *(float4*)&qf[0]  = sm.u.a.ql4[h*4+0];
        *(float4*)&qf[4]  = sm.u.a.ql4[h*4+1];
        *(float4*)&qf[8]  = sm.u.a.ql4[h*4+2];
        *(float4*)&qf[12] = sm.u.a.ql4[h*4+3];
        float dot = 0.f;
        #pragma unroll
        for (int j = 0; j < 16; ++j) dot = fmaf(qf[j], kf[j], dot);
        float kpf[12];
        unp4(kpr[3*h+0], kpf); unp4(kpr[3*h+1], kpf+4); unp4(kpr[3*h+2], kpf+8);
        float qpf[12];
        *(float4*)&qpf[0] = sm.u.a.qpl4[h*4+0];
        *(float4*)&qpf[4] = sm.u.a.qpl4[h*4+1];
        *(float4*)&qpf[8] = sm.u.a.qpl4[h*4+2];
        float pts = 0.f;
        #pragma unroll
        for (int p = 0; p < 4; ++p) {
          float dx = qpf[p*3+0]-kpf[p*3+0];
          float dy = qpf[p*3+1]-kpf[p*3+1];
          float dz = qpf[p*3+2]-kpf[p*3+2];
          pts += dx*dx + dy*dy + dz*dz;
        }
        sm.probs[h*NT + kk] = dot * 0.14433756729740643f
                            + accb[r][h] * 0.57735026918962576f
                            + sm.u.a.hwc[h] * pts + maskterm;
      }
    }
  }
  __syncthreads();

  // ---- Phase B: softmax (wave w -> heads w, w+4, w+8), float4 accesses ----
  {
    const int wave = tid >> 6, lane = tid & 63;
    #pragma unroll
    for (int hh = 0; hh < 3; ++hh) {
      const int h = wave + hh*4;
      float4* P4 = (float4*)sm.probs + h*192;
      float4 v0 = P4[lane], v1 = P4[64+lane], v2 = P4[128+lane];
      float m = fmaxf(fmaxf(fmaxf(v0.x,v0.y),fmaxf(v0.z,v0.w)),
                fmaxf(fmaxf(fmaxf(v1.x,v1.y),fmaxf(v1.z,v1.w)),
                      fmaxf(fmaxf(v2.x,v2.y),fmaxf(v2.z,v2.w))));
      #pragma unroll
      for (int off = 32; off; off >>= 1) m = fmaxf(m, __shfl_xor(m, off, 64));
      v0.x=__expf(v0.x-m); v0.y=__expf(v0.y-m); v0.z=__expf(v0.z-m); v0.w=__expf(v0.w-m);
      v1.x=__expf(v1.x-m); v1.y=__expf(v1.y-m); v1.z=__expf(v1.z-m); v1.w=__expf(v1.w-m);
      v2.x=__expf(v2.x-m); v2.y=__expf(v2.y-m); v2.z=__expf(v2.z-m); v2.w=__expf(v2.w-m);
      float ssum = (v0.x+v0.y+v0.z+v0.w) + (v1.x+v1.y+v1.z+v1.w) + (v2.x+v2.y+v2.z+v2.w);
      #pragma unroll
      for (int off = 32; off; off >>= 1) ssum += __shfl_xor(ssum, off, 64);
      const float inv = 1.0f / ssum;
      v0.x*=inv; v0.y*=inv; v0.z*=inv; v0.w*=inv;
      v1.x*=inv; v1.y*=inv; v1.z*=inv; v1.w*=inv;
      v2.x*=inv; v2.y*=inv; v2.z*=inv; v2.w*=inv;
      P4[lane]=v0; P4[64+lane]=v1; P4[128+lane]=v2;
    }
  }
  __syncthreads();

  // ---- Phase C1: o_pair (2nd z pass). Wave covers a full 512B z row per
  // instruction: lane = channel-pair, wave = 3-head group. probs broadcast b128.
  {
    const int c2 = (tid & 63) * 2;
    const int h0 = (tid >> 6) * 3;
    const float4* p0 = (const float4*)(sm.probs + (h0+0)*NT);
    const float4* p1 = (const float4*)(sm.probs + (h0+1)*NT);
    const float4* p2 = (const float4*)(sm.probs + (h0+2)*NT);
    const size_t zrb = (size_t)qrow*ZROWE;
    float a00=0.f,a01=0.f,a10=0.f,a11=0.f,a20=0.f,a21=0.f;
    #pragma unroll 2
    for (int tt = 0; tt < 192; ++tt) {
      float4 pa = p0[tt], pb = p1[tt], pc = p2[tt];
      #pragma unroll
      for (int e = 0; e < 4; ++e) {
        float zx, zy;
        ld2<BF16>(z, zrb + (size_t)(tt*4+e)*128 + c2, zx, zy);
        const float w0 = f4get(pa,e), w1 = f4get(pb,e), w2 = f4get(pc,e);
        a00 = fmaf(w0, zx, a00); a01 = fmaf(w0, zy, a01);
        a10 = fmaf(w1, zx, a10); a11 = fmaf(w1, zy, a11);
        a20 = fmaf(w2, zx, a20); a21 = fmaf(w2, zy, a21);
      }
    }
    sm.u.c.catrow[576 + (h0+0)*128 + c2]   = a00;
    sm.u.c.catrow[576 + (h0+0)*128 + c2+1] = a01;
    sm.u.c.catrow[576 + (h0+1)*128 + c2]   = a10;
    sm.u.c.catrow[576 + (h0+1)*128 + c2+1] = a11;
    sm.u.c.catrow[576 + (h0+2)*128 + c2]   = a20;
    sm.u.c.catrow[576 + (h0+2)*128 + c2+1] = a21;
  }

  // ---- Phase C2: o (192) and o_pt global-frame sums (288), transposed
  // bf16 workspace -> uint4 streaming loads, probs as b128 broadcast ----
  for (int idx = tid; idx < 480; idx += 256) {
    const ushort_t* src; int h;
    if (idx < 192) { h = idx >> 4;            src = vTB  + (size_t)idx*NT; }
    else           { const int j = idx - 192; h = j/24;  src = vpTB + (size_t)j*NT; }
    const uint4*  s4 = (const uint4*)src;
    const float4* pr = (const float4*)(sm.probs + h*NT);
    float acc = 0.f;
    #pragma unroll 2
    for (int tt = 0; tt < 96; ++tt) {
      float vf[8]; unp8(s4[tt], vf);
      float4 pa = pr[2*tt], pb = pr[2*tt+1];
      acc = fmaf(pa.x, vf[0], acc); acc = fmaf(pa.y, vf[1], acc);
      acc = fmaf(pa.z, vf[2], acc); acc = fmaf(pa.w, vf[3], acc);
      acc = fmaf(pb.x, vf[4], acc); acc = fmaf(pb.y, vf[5], acc);
      acc = fmaf(pb.z, vf[6], acc); acc = fmaf(pb.w, vf[7], acc);
    }
    if (idx < 192) sm.u.c.catrow[idx]   = acc;
    else           sm.u.c.opt[idx-192]  = acc;
  }
  __syncthreads();

  // ---- Phase D: inverse rigid, norms ----
  if (tid < 96) {
    const int h = tid >> 3, p = tid & 7;
    const int j = h*24 + p*3;
    float gx = sm.u.c.opt[j], gy = sm.u.c.opt[j+1], gz = sm.u.c.opt[j+2];
    gx -= ld<BF16>(tg, qrow*3+0); gy -= ld<BF16>(tg, qrow*3+1); gz -= ld<BF16>(tg, qrow*3+2);
    float r[9];
    #pragma unroll
    for (int i = 0; i < 9; ++i) r[i] = ld<BF16>(Rg, qrow*9 + i);
    float lx = r[0]*gx + r[3]*gy + r[6]*gz;   // R^T * g
    float ly = r[1]*gx + r[4]*gy + r[7]*gz;
    float lz = r[2]*gx + r[5]*gy + r[8]*gz;
    float nrm = sqrtf(lx*lx + ly*ly + lz*lz + 1e-8f);
    const int jj = h*8 + p;
    sm.u.c.catrow[192 + jj] = lx;
    sm.u.c.catrow[288 + jj] = ly;
    sm.u.c.catrow[384 + jj] = lz;
    sm.u.c.catrow[480 + jj] = nrm;
  }
  __syncthreads();   // all z reads done before scribbling z

  {
    float* crow;
    if constexpr (BF16) crow = (float*)((ushort_t*)z + (size_t)qrow*ZROWE);
    else                crow = (float*)z + (size_t)qrow*ZROWE;
    float4* c4p = (float4*)crow;
    const float4* src4 = (const float4*)sm.u.c.catrow;
    for (int i = tid; i < 528; i += 256) c4p[i] = src4[i];
  }
}

__global__ __launch_bounds__(256, 3)
void k_attn(const int* flag,
            void* z, const void* Rg, const void* tg, const void* mg,
            const void* Wb, const void* bbp, const void* hwg,
            const ushort_t* qB, const ushort_t* kB, const ushort_t* vTB,
            const ushort_t* qpB, const ushort_t* kpB, const ushort_t* vpTB)
{
  __shared__ AttnSmem sm;
  if (*flag) attn_body<true >(sm, z,Rg,tg,mg,Wb,bbp,hwg,qB,kB,vTB,qpB,kpB,vpTB);
  else       attn_body<false>(sm, z,Rg,tg,mg,Wb,bbp,hwg,qB,kB,vTB,qpB,kpB,vpTB);
}

// ---------------------------------------------------------------------------
// Kernel 3: out = cat(768x2112, strided in z) @ Wout(2112x384) + bout
// ---------------------------------------------------------------------------
struct OutSmem { float As[32][33]; float Bs[32][33]; };

template<bool BF16>
__device__ void out_body(OutSmem& sm, const void* zcat, const void* Wout,
                         const void* bout, void* out)
{
  const size_t RS = BF16 ? 49152 : 98304;   // float stride of cat rows in z
  const float* cat = (const float*)zcat;
  const int n0 = blockIdx.x * 32, m0 = blockIdx.y * 32, tid = threadIdx.x;
  const int tm = (tid >> 4) * 2, tn = (tid & 15) * 2;
  float acc00 = 0.f, acc01 = 0.f, acc10 = 0.f, acc11 = 0.f;
  const int e = tid * 4;
  const int lm = e >> 5, lk = e & 31;
  for (int k0 = 0; k0 < 2112; k0 += 32) {
    float4 a = *(const float4*)(cat + (size_t)(m0 + lm)*RS + k0 + lk);
    sm.As[lk+0][lm] = a.x; sm.As[lk+1][lm] = a.y; sm.As[lk+2][lm] = a.z; sm.As[lk+3][lm] = a.w;
    float bw[4];
    ld4<BF16>(Wout, (size_t)(k0 + lm)*384 + n0 + lk, bw);
    sm.Bs[lm][lk+0] = bw[0]; sm.Bs[lm][lk+1] = bw[1];
    sm.Bs[lm][lk+2] = bw[2]; sm.Bs[lm][lk+3] = bw[3];
    __syncthreads();
    #pragma unroll
    for (int kk = 0; kk < 32; ++kk) {
      float a0 = sm.As[kk][tm], a1 = sm.As[kk][tm+1];
      float b0 = sm.Bs[kk][tn], b1 = sm.Bs[kk][tn+1];
      acc00 = fmaf(a0,b0,acc00); acc01 = fmaf(a0,b1,acc01);
      acc10 = fmaf(a1,b0,acc10); acc11 = fmaf(a1,b1,acc11);
    }
    __syncthreads();
  }
  float bb0 = ld<BF16>(bout, n0+tn), bb1 = ld<BF16>(bout, n0+tn+1);
  float v00 = acc00+bb0, v01 = acc01+bb1, v10 = acc10+bb0, v11 = acc11+bb1;
  if constexpr (BF16) {
    ushort_t* o = (ushort_t*)out;
    o[(size_t)(m0+tm)*384   + n0+tn]   = f2bf(v00);
    o[(size_t)(m0+tm)*384   + n0+tn+1] = f2bf(v01);
    o[(size_t)(m0+tm+1)*384 + n0+tn]   = f2bf(v10);
    o[(size_t)(m0+tm+1)*384 + n0+tn+1] = f2bf(v11);
  } else {
    float* o = (float*)out;
    o[(size_t)(m0+tm)*384   + n0+tn]   = v00;
    o[(size_t)(m0+tm)*384   + n0+tn+1] = v01;
    o[(size_t)(m0+tm+1)*384 + n0+tn]   = v10;
    o[(size_t)(m0+tm+1)*384 + n0+tn+1] = v11;
  }
}

__global__ __launch_bounds__(256)
void k_out(const int* flag, const void* zcat, const void* Wout,
           const void* bout, void* out)
{
  __shared__ OutSmem sm;
  if (*flag) out_body<true >(sm, zcat, Wout, bout, out);
  else       out_body<false>(sm, zcat, Wout, bout, out);
}

// ---------------------------------------------------------------------------
extern "C" void kernel_launch(void* const* d_in, const int* in_sizes, int n_in,
                              void* d_out, int out_size, void* d_ws, size_t ws_size,
                              hipStream_t stream) {
  const void* s    = d_in[0];
  void*       z    = d_in[1];   // also cat scratch (row-private)
  const void* R    = d_in[2];
  const void* t    = d_in[3];
  const void* mask = d_in[4];
  const void* Wq   = d_in[5];
  const void* bq   = d_in[6];
  const void* Wkv  = d_in[7];
  const void* bkv  = d_in[8];
  const void* Wqp  = d_in[9];
  const void* bqp  = d_in[10];
  const void* Wkvp = d_in[11];
  const void* bkvp = d_in[12];
  const void* Wb   = d_in[13];
  const void* bb   = d_in[14];
  const void* hw   = d_in[15];
  const void* Wout = d_in[16];
  const void* bout = d_in[17];

  int* flag = (int*)d_ws;
  ushort_t* base = (ushort_t*)((char*)d_ws + 64);
  ushort_t* qB   = base;                 // 768*192
  ushort_t* kB   = qB   + 147456;        // 768*192
  ushort_t* vTB  = kB   + 147456;        // [192][768]
  ushort_t* qpB  = vTB  + 147456;        // 768*144
  ushort_t* kpB  = qpB  + 110592;        // 768*144
  ushort_t* vpTB = kpB  + 110592;        // [288][768]  (total 1.77 MB + 64 B)

  k_detect<<<dim3(1), dim3(64), 0, stream>>>(s, flag);
  k_proj<<<dim3(768), dim3(256), 0, stream>>>(flag, s, R, t, Wq, bq, Wkv, bkv,
                                              Wqp, bqp, Wkvp, bkvp,
                                              qB, kB, vTB, qpB, kpB, vpTB);
  k_attn<<<dim3(768), dim3(256), 0, stream>>>(flag, z, R, t, mask, Wb, bb, hw,
                                              qB, kB, vTB, qpB, kpB, vpTB);
  k_out<<<dim3(12, 24), dim3(256), 0, stream>>>(flag, z, Wout, bout, d_out);
}

// Round 2
// 977.132 us; speedup vs baseline: 1.1779x; 1.1779x over previous
//
#include <hip/hip_runtime.h>

// StructureModule (IPA), B=1, N=768. Harness dtype ambiguous (bf16 vs fp32):
// a detect kernel sniffs s[] bit patterns and all kernels branch on the flag.
// dims: C_S=384, C_Z=128, C_H=16, H=12, PQ=4, PV=8, CO=2112
// rocprof r0: FETCH ~305MB = one fp32 z pass -> runtime dtype is fp32.
// rocprof r1 LESSON: fusing 3 kk-rows/thread in phase A ballooned the live
// cacheline set (49KB/block > L1, >L2 aggregate) -> 4.5 z-passes from HBM.
// Phase A must consume each 64B line of z IMMEDIATELY (full-chunk loads),
// never rely on cache retention across a strided sweep.

typedef unsigned short ushort_t;

__device__ __forceinline__ float bfr(ushort_t u) {
  return __uint_as_float(((unsigned int)u) << 16);
}
__device__ __forceinline__ ushort_t f2bf(float f) {
  unsigned int u = __float_as_uint(f);
  u += 0x7FFFu + ((u >> 16) & 1u);
  return (ushort_t)(u >> 16);
}

template<bool BF16>
__device__ __forceinline__ float ld(const void* p, size_t i) {
  if constexpr (BF16) return bfr(((const ushort_t*)p)[i]);
  else                return ((const float*)p)[i];
}
template<bool BF16>
__device__ __forceinline__ void ld4(const void* p, size_t i, float* o) {
  if constexpr (BF16) {
    uint2 u = *(const uint2*)((const ushort_t*)p + i);   // i multiple of 4
    o[0]=__uint_as_float(u.x<<16); o[1]=__uint_as_float(u.x & 0xffff0000u);
    o[2]=__uint_as_float(u.y<<16); o[3]=__uint_as_float(u.y & 0xffff0000u);
  } else {
    float4 v = *(const float4*)((const float*)p + i);
    o[0]=v.x; o[1]=v.y; o[2]=v.z; o[3]=v.w;
  }
}
template<bool BF16>
__device__ __forceinline__ void ld2(const void* p, size_t i, float& x, float& y) {
  if constexpr (BF16) {
    unsigned int u = *(const unsigned int*)((const ushort_t*)p + i);  // i even
    x = __uint_as_float(u << 16); y = __uint_as_float(u & 0xffff0000u);
  } else {
    float2 v = *(const float2*)((const float*)p + i);
    x = v.x; y = v.y;
  }
}
__device__ __forceinline__ void unp8(uint4 v, float* f) {
  f[0]=__uint_as_float(v.x<<16); f[1]=__uint_as_float(v.x&0xffff0000u);
  f[2]=__uint_as_float(v.y<<16); f[3]=__uint_as_float(v.y&0xffff0000u);
  f[4]=__uint_as_float(v.z<<16); f[5]=__uint_as_float(v.z&0xffff0000u);
  f[6]=__uint_as_float(v.w<<16); f[7]=__uint_as_float(v.w&0xffff0000u);
}
__device__ __forceinline__ void unp4(uint2 v, float* f) {
  f[0]=__uint_as_float(v.x<<16); f[1]=__uint_as_float(v.x&0xffff0000u);
  f[2]=__uint_as_float(v.y<<16); f[3]=__uint_as_float(v.y&0xffff0000u);
}
// 16 consecutive floats (one 64B line fp32 / 32B bf16), fully consumed by caller
template<bool BF16>
__device__ __forceinline__ void ld16(const void* p, size_t i, float* o) {
  if constexpr (BF16) {
    const uint4* q = (const uint4*)((const ushort_t*)p + i);
    unp8(q[0], o); unp8(q[1], o+8);
  } else {
    const float4* q = (const float4*)((const float*)p + i);
    *(float4*)&o[0]=q[0]; *(float4*)&o[4]=q[1];
    *(float4*)&o[8]=q[2]; *(float4*)&o[12]=q[3];
  }
}
__device__ __forceinline__ float f4get(float4 v, int e) {   // e compile-time after unroll
  return e==0 ? v.x : (e==1 ? v.y : (e==2 ? v.z : v.w));
}

#define NT 768
#define ZROWE 98304   /* elements per z q-row: 768*128 */

// ---------------------------------------------------------------------------
// dtype sniffer: bf16 pairs -> bits[14:7] of each word are a N(0,1) exponent
// ---------------------------------------------------------------------------
__global__ void k_detect(const void* s, int* flag) {
  if (blockIdx.x == 0 && threadIdx.x == 0) {
    const unsigned int* w = (const unsigned int*)s;
    int cnt = 0;
    for (int i = 0; i < 256; ++i) {
      unsigned int e = (w[i] >> 7) & 0xFFu;
      cnt += (e >= 118u && e <= 131u) ? 1 : 0;
    }
    *flag = (cnt >= 128) ? 1 : 0;
  }
}

// ---------------------------------------------------------------------------
// Kernel 1: projections -> bf16 workspace
//   q  [n][192]           k  [n][h*16+c]      vT [c(192)][n]   (transposed!)
//   qp [n][144]           kp [n][h*12+p*3+i]  vpT[j(288)][n]   (transposed!)
// ---------------------------------------------------------------------------
struct ProjSmem {
  float sl[384];
  float pbuf[576];
  float Rl[9];
  float tl[3];
};

template<bool BF16>
__device__ void proj_body(ProjSmem& sm,
            const void* s, const void* R, const void* t,
            const void* Wq, const void* bq, const void* Wkv, const void* bkv,
            const void* Wqp, const void* bqp, const void* Wkvp, const void* bkvp,
            ushort_t* qo, ushort_t* ko, ushort_t* vTo,
            ushort_t* qpo, ushort_t* kpo, ushort_t* vpTo)
{
  const int n = blockIdx.x, tid = threadIdx.x;
  for (int i = tid; i < 96; i += 256) {
    float f[4]; ld4<BF16>(s, (size_t)n*384 + i*4, f);
    *(float4*)&sm.sl[i*4] = make_float4(f[0],f[1],f[2],f[3]);
  }
  if (tid >= 128 && tid < 137) sm.Rl[tid-128] = ld<BF16>(R, (size_t)n*9 + (tid-128));
  if (tid >= 160 && tid < 163) sm.tl[tid-160] = ld<BF16>(t, (size_t)n*3 + (tid-160));
  __syncthreads();

  for (int g = tid; g < 288; g += 256) {     // 288 quads of 4 output cols
    const void* W; const void* bias; int ldw, cj;
    if (g < 48)       { W=Wq;   bias=bq;   ldw=192; cj=g*4;       }
    else if (g < 144) { W=Wkv;  bias=bkv;  ldw=384; cj=g*4-192;   }
    else if (g < 180) { W=Wqp;  bias=bqp;  ldw=144; cj=g*4-576;   }
    else              { W=Wkvp; bias=bkvp; ldw=432; cj=g*4-720;   }
    float a0 = ld<BF16>(bias, cj+0), a1 = ld<BF16>(bias, cj+1),
          a2 = ld<BF16>(bias, cj+2), a3 = ld<BF16>(bias, cj+3);
    #pragma unroll 4
    for (int i = 0; i < 384; ++i) {
      float w[4]; ld4<BF16>(W, (size_t)i*ldw + cj, w);
      const float sv = sm.sl[i];
      a0 = fmaf(sv, w[0], a0); a1 = fmaf(sv, w[1], a1);
      a2 = fmaf(sv, w[2], a2); a3 = fmaf(sv, w[3], a3);
    }
    const int j = g*4;
    if (j < 192) {
      ushort_t* d = qo + (size_t)n*192 + j;
      d[0]=f2bf(a0); d[1]=f2bf(a1); d[2]=f2bf(a2); d[3]=f2bf(a3);
    } else if (j < 576) {
      const int c = j - 192, h = c >> 5, r = c & 31;   // quad stays in one half
      if (r < 16) {
        ushort_t* d = ko + (size_t)n*192 + h*16 + r;
        d[0]=f2bf(a0); d[1]=f2bf(a1); d[2]=f2bf(a2); d[3]=f2bf(a3);
      } else {
        const int cc = h*16 + (r-16);
        vTo[(size_t)(cc+0)*NT + n] = f2bf(a0);
        vTo[(size_t)(cc+1)*NT + n] = f2bf(a1);
        vTo[(size_t)(cc+2)*NT + n] = f2bf(a2);
        vTo[(size_t)(cc+3)*NT + n] = f2bf(a3);
      }
    } else {
      *(float4*)&sm.pbuf[j-576] = make_float4(a0,a1,a2,a3);
    }
  }
  __syncthreads();

  if (tid < 48) {   // q points: j -> (h=j/4, pq=j%4); store [n][j*3+i]
    const int j = tid;
    float lx = sm.pbuf[j], ly = sm.pbuf[48+j], lz = sm.pbuf[96+j];
    #pragma unroll
    for (int i = 0; i < 3; ++i) {
      float g = sm.Rl[i*3+0]*lx + sm.Rl[i*3+1]*ly + sm.Rl[i*3+2]*lz + sm.tl[i];
      qpo[(size_t)n*144 + j*3 + i] = f2bf(g);
    }
  } else if (tid >= 64 && tid < 208) {  // kv points
    const int j = tid - 64;
    float lx = sm.pbuf[144+j], ly = sm.pbuf[288+j], lz = sm.pbuf[432+j];
    const int h = j / 12, pp = j % 12;
    #pragma unroll
    for (int i = 0; i < 3; ++i) {
      float g = sm.Rl[i*3+0]*lx + sm.Rl[i*3+1]*ly + sm.Rl[i*3+2]*lz + sm.tl[i];
      if (pp < 4) kpo[(size_t)n*144 + h*12 + pp*3 + i]         = f2bf(g);
      else        vpTo[(size_t)(h*24 + (pp-4)*3 + i)*NT + n]   = f2bf(g);
    }
  }
}

__global__ __launch_bounds__(256)
void k_proj(const int* flag,
            const void* s, const void* R, const void* t,
            const void* Wq, const void* bq, const void* Wkv, const void* bkv,
            const void* Wqp, const void* bqp, const void* Wkvp, const void* bkvp,
            ushort_t* qo, ushort_t* ko, ushort_t* vTo,
            ushort_t* qpo, ushort_t* kpo, ushort_t* vpTo)
{
  __shared__ ProjSmem sm;
  if (*flag) proj_body<true >(sm, s,R,t,Wq,bq,Wkv,bkv,Wqp,bqp,Wkvp,bkvp,qo,ko,vTo,qpo,kpo,vpTo);
  else       proj_body<false>(sm, s,R,t,Wq,bq,Wkv,bkv,Wqp,bqp,Wkvp,bkvp,qo,ko,vTo,qpo,kpo,vpTo);
}

// ---------------------------------------------------------------------------
// Kernel 2: per-query-row attention; cat row scribbled into own (dead) z row.
// LDS union {phase-A: Wb,q,qp} / {phase-C: catrow,opt} -> 45.4KB -> 3 blk/CU.
// ---------------------------------------------------------------------------
struct __align__(16) AttnSmem {
  float probs[12 * NT];            // 36864 B, alive A..C
  union {
    struct {
      float4 Wbl[128*3];           // [c][h-quad]  6144 B
      float4 ql4[12*4];            // [h][16 floats] 768 B
      float4 qpl4[12*4];           // [h][12 used + 4 pad] 768 B
      float  hwc[12], bbl[12];     // 96 B
    } a;                            // 7776 B
    struct {
      float catrow[2112];          // 8448 B
      float opt[288];              // 1152 B
    } c;                            // 9600 B
  } u;
};  // 46464 B total -> 3 blocks/CU (3*46464 <= 163840)

template<bool BF16>
__device__ void attn_body(AttnSmem& sm,
            void* z, const void* Rg, const void* tg, const void* mg,
            const void* Wb, const void* bbp, const void* hwg,
            const ushort_t* qB, const ushort_t* kB, const ushort_t* vTB,
            const ushort_t* qpB, const ushort_t* kpB, const ushort_t* vpTB)
{
  const int qrow = blockIdx.x, tid = threadIdx.x;

  // ---- stage A-phase smem ----
  for (int i = tid; i < 128*12; i += 256) ((float*)sm.u.a.Wbl)[i] = ld<BF16>(Wb, i);
  if (tid < 48) {                       // q: 12h x 16, as float4s
    const int h = tid >> 2, part = tid & 3;
    float f[4];
    unp4(*(const uint2*)(qB + (size_t)qrow*192 + h*16 + part*4), f);
    sm.u.a.ql4[h*4+part] = make_float4(f[0],f[1],f[2],f[3]);
  } else if (tid >= 64 && tid < 112) {  // qp: 12h x 12 -> padded [h][16]
    const int j = tid - 64, h = j >> 2, part = j & 3;
    if (part < 3) {
      float f[4];
      unp4(*(const uint2*)(qpB + (size_t)qrow*144 + h*12 + part*4), f);
      sm.u.a.qpl4[h*4+part] = make_float4(f[0],f[1],f[2],f[3]);
    }
  } else if (tid >= 192 && tid < 204) {
    const int h = tid - 192;
    float x = ld<BF16>(hwg, h);
    float sp = (x > 20.f) ? x : log1pf(expf(x));     // softplus
    sm.u.a.hwc[h] = -0.5f * sp * 0.13608276348795434f;   // * sqrt(1/54), fold -0.5
    sm.u.a.bbl[h] = ld<BF16>(bbp, h);
  }
  __syncthreads();
  const float mq = ld<BF16>(mg, qrow);

  // ---- Phase A: logits. ONE kk-row at a time (r1 lesson: no cross-row
  // fusion); z read in full 64B chunks, register-double-buffered so each
  // cacheline is fetched once and consumed immediately. ----
  {
    const float4* Wb4 = sm.u.a.Wbl;
    for (int r = 0; r < 3; ++r) {
      const int kk = tid + r*256;
      float accb[12];
      #pragma unroll
      for (int h = 0; h < 12; ++h) accb[h] = sm.u.a.bbl[h];
      const size_t zb = ((size_t)qrow*NT + kk)*128;
      float zb0[16], zb1[16];
      ld16<BF16>(z, zb, zb0);
      #pragma unroll
      for (int c16 = 0; c16 < 8; ++c16) {
        float* cur = (c16 & 1) ? zb1 : zb0;
        float* nxt = (c16 & 1) ? zb0 : zb1;
        if (c16 < 7) ld16<BF16>(z, zb + (size_t)(c16+1)*16, nxt);
        #pragma unroll
        for (int e = 0; e < 16; ++e) {
          const int c = c16*16 + e;
          float wr[12];
          *(float4*)&wr[0] = Wb4[c*3+0];
          *(float4*)&wr[4] = Wb4[c*3+1];
          *(float4*)&wr[8] = Wb4[c*3+2];
          const float zc = cur[e];
          #pragma unroll
          for (int h = 0; h < 12; ++h) accb[h] = fmaf(zc, wr[h], accb[h]);
        }
      }
      const uint4* kr  = (const uint4*)(kB  + (size_t)kk*192);  // 16B-aligned
      const uint2* kpr = (const uint2*)(kpB + (size_t)kk*144);  // 8B-aligned
      const float mk = ld<BF16>(mg, kk);
      const float maskterm = 100000.0f * (mq*mk - 1.0f);
      #pragma unroll
      for (int h = 0; h < 12; ++h) {
        float kf[16];
        unp8(kr[2*h+0], kf); unp8(kr[2*h+1], kf+8);
        float qf[16];
        *(float4*)&qf[0]  = sm.u.a.ql4[h*4+0];
        *(float4*)&qf[4]  = sm.u.a.ql4[h*4+1];
        *(float4*)&qf[8]  = sm.u.a.ql4[h*4+2];
        *(float4*)&qf[12] = sm.u.a.ql4[h*4+3];
        float dot = 0.f;
        #pragma unroll
        for (int j = 0; j < 16; ++j) dot = fmaf(qf[j], kf[j], dot);
        float kpf[12];
        unp4(kpr[3*h+0], kpf); unp4(kpr[3*h+1], kpf+4); unp4(kpr[3*h+2], kpf+8);
        float qpf[12];
        *(float4*)&qpf[0] = sm.u.a.qpl4[h*4+0];
        *(float4*)&qpf[4] = sm.u.a.qpl4[h*4+1];
        *(float4*)&qpf[8] = sm.u.a.qpl4[h*4+2];
        float pts = 0.f;
        #pragma unroll
        for (int p = 0; p < 4; ++p) {
          float dx = qpf[p*3+0]-kpf[p*3+0];
          float dy = qpf[p*3+1]-kpf[p*3+1];
          float dz = qpf[p*3+2]-kpf[p*3+2];
          pts += dx*dx + dy*dy + dz*dz;
        }
        sm.probs[h*NT + kk] = dot * 0.14433756729740643f
                            + accb[h] * 0.57735026918962576f
                            + sm.u.a.hwc[h] * pts + maskterm;
      }
    }
  }
  __syncthreads();

  // ---- Phase B: softmax (wave w -> heads w, w+4, w+8), float4 accesses ----
  {
    const int wave = tid >> 6, lane = tid & 63;
    #pragma unroll
    for (int hh = 0; hh < 3; ++hh) {
      const int h = wave + hh*4;
      float4* P4 = (float4*)sm.probs + h*192;
      float4 v0 = P4[lane], v1 = P4[64+lane], v2 = P4[128+lane];
      float m = fmaxf(fmaxf(fmaxf(v0.x,v0.y),fmaxf(v0.z,v0.w)),
                fmaxf(fmaxf(fmaxf(v1.x,v1.y),fmaxf(v1.z,v1.w)),
                      fmaxf(fmaxf(v2.x,v2.y),fmaxf(v2.z,v2.w))));
      #pragma unroll
      for (int off = 32; off; off >>= 1) m = fmaxf(m, __shfl_xor(m, off, 64));
      v0.x=__expf(v0.x-m); v0.y=__expf(v0.y-m); v0.z=__expf(v0.z-m); v0.w=__expf(v0.w-m);
      v1.x=__expf(v1.x-m); v1.y=__expf(v1.y-m); v1.z=__expf(v1.z-m); v1.w=__expf(v1.w-m);
      v2.x=__expf(v2.x-m); v2.y=__expf(v2.y-m); v2.z=__expf(v2.z-m); v2.w=__expf(v2.w-m);
      float ssum = (v0.x+v0.y+v0.z+v0.w) + (v1.x+v1.y+v1.z+v1.w) + (v2.x+v2.y+v2.z+v2.w);
      #pragma unroll
      for (int off = 32; off; off >>= 1) ssum += __shfl_xor(ssum, off, 64);
      const float inv = 1.0f / ssum;
      v0.x*=inv; v0.y*=inv; v0.z*=inv; v0.w*=inv;
      v1.x*=inv; v1.y*=inv; v1.z*=inv; v1.w*=inv;
      v2.x*=inv; v2.y*=inv; v2.z*=inv; v2.w*=inv;
      P4[lane]=v0; P4[64+lane]=v1; P4[128+lane]=v2;
    }
  }
  __syncthreads();

  // ---- Phase C1: o_pair (2nd z pass). Wave covers a full 512B z row per
  // instruction: lane = channel-pair, wave = 3-head group. probs broadcast b128.
  {
    const int c2 = (tid & 63) * 2;
    const int h0 = (tid >> 6) * 3;
    const float4* p0 = (const float4*)(sm.probs + (h0+0)*NT);
    const float4* p1 = (const float4*)(sm.probs + (h0+1)*NT);
    const float4* p2 = (const float4*)(sm.probs + (h0+2)*NT);
    const size_t zrb = (size_t)qrow*ZROWE;
    float a00=0.f,a01=0.f,a10=0.f,a11=0.f,a20=0.f,a21=0.f;
    #pragma unroll 2
    for (int tt = 0; tt < 192; ++tt) {
      float4 pa = p0[tt], pb = p1[tt], pc = p2[tt];
      #pragma unroll
      for (int e = 0; e < 4; ++e) {
        float zx, zy;
        ld2<BF16>(z, zrb + (size_t)(tt*4+e)*128 + c2, zx, zy);
        const float w0 = f4get(pa,e), w1 = f4get(pb,e), w2 = f4get(pc,e);
        a00 = fmaf(w0, zx, a00); a01 = fmaf(w0, zy, a01);
        a10 = fmaf(w1, zx, a10); a11 = fmaf(w1, zy, a11);
        a20 = fmaf(w2, zx, a20); a21 = fmaf(w2, zy, a21);
      }
    }
    sm.u.c.catrow[576 + (h0+0)*128 + c2]   = a00;
    sm.u.c.catrow[576 + (h0+0)*128 + c2+1] = a01;
    sm.u.c.catrow[576 + (h0+1)*128 + c2]   = a10;
    sm.u.c.catrow[576 + (h0+1)*128 + c2+1] = a11;
    sm.u.c.catrow[576 + (h0+2)*128 + c2]   = a20;
    sm.u.c.catrow[576 + (h0+2)*128 + c2+1] = a21;
  }

  // ---- Phase C2: o (192) and o_pt global-frame sums (288), transposed
  // bf16 workspace -> uint4 streaming loads, probs as b128 broadcast ----
  for (int idx = tid; idx < 480; idx += 256) {
    const ushort_t* src; int h;
    if (idx < 192) { h = idx >> 4;            src = vTB  + (size_t)idx*NT; }
    else           { const int j = idx - 192; h = j/24;  src = vpTB + (size_t)j*NT; }
    const uint4*  s4 = (const uint4*)src;
    const float4* pr = (const float4*)(sm.probs + h*NT);
    float acc = 0.f;
    #pragma unroll 2
    for (int tt = 0; tt < 96; ++tt) {
      float vf[8]; unp8(s4[tt], vf);
      float4 pa = pr[2*tt], pb = pr[2*tt+1];
      acc = fmaf(pa.x, vf[0], acc); acc = fmaf(pa.y, vf[1], acc);
      acc = fmaf(pa.z, vf[2], acc); acc = fmaf(pa.w, vf[3], acc);
      acc = fmaf(pb.x, vf[4], acc); acc = fmaf(pb.y, vf[5], acc);
      acc = fmaf(pb.z, vf[6], acc); acc = fmaf(pb.w, vf[7], acc);
    }
    if (idx < 192) sm.u.c.catrow[idx]   = acc;
    else           sm.u.c.opt[idx-192]  = acc;
  }
  __syncthreads();

  // ---- Phase D: inverse rigid, norms ----
  if (tid < 96) {
    const int h = tid >> 3, p = tid & 7;
    const int j = h*24 + p*3;
    float gx = sm.u.c.opt[j], gy = sm.u.c.opt[j+1], gz = sm.u.c.opt[j+2];
    gx -= ld<BF16>(tg, qrow*3+0); gy -= ld<BF16>(tg, qrow*3+1); gz -= ld<BF16>(tg, qrow*3+2);
    float r[9];
    #pragma unroll
    for (int i = 0; i < 9; ++i) r[i] = ld<BF16>(Rg, qrow*9 + i);
    float lx = r[0]*gx + r[3]*gy + r[6]*gz;   // R^T * g
    float ly = r[1]*gx + r[4]*gy + r[7]*gz;
    float lz = r[2]*gx + r[5]*gy + r[8]*gz;
    float nrm = sqrtf(lx*lx + ly*ly + lz*lz + 1e-8f);
    const int jj = h*8 + p;
    sm.u.c.catrow[192 + jj] = lx;
    sm.u.c.catrow[288 + jj] = ly;
    sm.u.c.catrow[384 + jj] = lz;
    sm.u.c.catrow[480 + jj] = nrm;
  }
  __syncthreads();   // all z reads done before scribbling z

  {
    float* crow;
    if constexpr (BF16) crow = (float*)((ushort_t*)z + (size_t)qrow*ZROWE);
    else                crow = (float*)z + (size_t)qrow*ZROWE;
    float4* c4p = (float4*)crow;
    const float4* src4 = (const float4*)sm.u.c.catrow;
    for (int i = tid; i < 528; i += 256) c4p[i] = src4[i];
  }
}

__global__ __launch_bounds__(256, 3)
void k_attn(const int* flag,
            void* z, const void* Rg, const void* tg, const void* mg,
            const void* Wb, const void* bbp, const void* hwg,
            const ushort_t* qB, const ushort_t* kB, const ushort_t* vTB,
            const ushort_t* qpB, const ushort_t* kpB, const ushort_t* vpTB)
{
  __shared__ AttnSmem sm;
  if (*flag) attn_body<true >(sm, z,Rg,tg,mg,Wb,bbp,hwg,qB,kB,vTB,qpB,kpB,vpTB);
  else       attn_body<false>(sm, z,Rg,tg,mg,Wb,bbp,hwg,qB,kB,vTB,qpB,kpB,vpTB);
}

// ---------------------------------------------------------------------------
// Kernel 3: out = cat(768x2112, strided in z) @ Wout(2112x384) + bout
// ---------------------------------------------------------------------------
struct OutSmem { float As[32][33]; float Bs[32][33]; };

template<bool BF16>
__device__ void out_body(OutSmem& sm, const void* zcat, const void* Wout,
                         const void* bout, void* out)
{
  const size_t RS = BF16 ? 49152 : 98304;   // float stride of cat rows in z
  const float* cat = (const float*)zcat;
  const int n0 = blockIdx.x * 32, m0 = blockIdx.y * 32, tid = threadIdx.x;
  const int tm = (tid >> 4) * 2, tn = (tid & 15) * 2;
  float acc00 = 0.f, acc01 = 0.f, acc10 = 0.f, acc11 = 0.f;
  const int e = tid * 4;
  const int lm = e >> 5, lk = e & 31;
  for (int k0 = 0; k0 < 2112; k0 += 32) {
    float4 a = *(const float4*)(cat + (size_t)(m0 + lm)*RS + k0 + lk);
    sm.As[lk+0][lm] = a.x; sm.As[lk+1][lm] = a.y; sm.As[lk+2][lm] = a.z; sm.As[lk+3][lm] = a.w;
    float bw[4];
    ld4<BF16>(Wout, (size_t)(k0 + lm)*384 + n0 + lk, bw);
    sm.Bs[lm][lk+0] = bw[0]; sm.Bs[lm][lk+1] = bw[1];
    sm.Bs[lm][lk+2] = bw[2]; sm.Bs[lm][lk+3] = bw[3];
    __syncthreads();
    #pragma unroll
    for (int kk = 0; kk < 32; ++kk) {
      float a0 = sm.As[kk][tm], a1 = sm.As[kk][tm+1];
      float b0 = sm.Bs[kk][tn], b1 = sm.Bs[kk][tn+1];
      acc00 = fmaf(a0,b0,acc00); acc01 = fmaf(a0,b1,acc01);
      acc10 = fmaf(a1,b0,acc10); acc11 = fmaf(a1,b1,acc11);
    }
    __syncthreads();
  }
  float bb0 = ld<BF16>(bout, n0+tn), bb1 = ld<BF16>(bout, n0+tn+1);
  float v00 = acc00+bb0, v01 = acc01+bb1, v10 = acc10+bb0, v11 = acc11+bb1;
  if constexpr (BF16) {
    ushort_t* o = (ushort_t*)out;
    o[(size_t)(m0+tm)*384   + n0+tn]   = f2bf(v00);
    o[(size_t)(m0+tm)*384   + n0+tn+1] = f2bf(v01);
    o[(size_t)(m0+tm+1)*384 + n0+tn]   = f2bf(v10);
    o[(size_t)(m0+tm+1)*384 + n0+tn+1] = f2bf(v11);
  } else {
    float* o = (float*)out;
    o[(size_t)(m0+tm)*384   + n0+tn]   = v00;
    o[(size_t)(m0+tm)*384   + n0+tn+1] = v01;
    o[(size_t)(m0+tm+1)*384 + n0+tn]   = v10;
    o[(size_t)(m0+tm+1)*384 + n0+tn+1] = v11;
  }
}

__global__ __launch_bounds__(256)
void k_out(const int* flag, const void* zcat, const void* Wout,
           const void* bout, void* out)
{
  __shared__ OutSmem sm;
  if (*flag) out_body<true >(sm, zcat, Wout, bout, out);
  else       out_body<false>(sm, zcat, Wout, bout, out);
}

// ---------------------------------------------------------------------------
extern "C" void kernel_launch(void* const* d_in, const int* in_sizes, int n_in,
                              void* d_out, int out_size, void* d_ws, size_t ws_size,
                              hipStream_t stream) {
  const void* s    = d_in[0];
  void*       z    = d_in[1];   // also cat scratch (row-private)
  const void* R    = d_in[2];
  const void* t    = d_in[3];
  const void* mask = d_in[4];
  const void* Wq   = d_in[5];
  const void* bq   = d_in[6];
  const void* Wkv  = d_in[7];
  const void* bkv  = d_in[8];
  const void* Wqp  = d_in[9];
  const void* bqp  = d_in[10];
  const void* Wkvp = d_in[11];
  const void* bkvp = d_in[12];
  const void* Wb   = d_in[13];
  const void* bb   = d_in[14];
  const void* hw   = d_in[15];
  const void* Wout = d_in[16];
  const void* bout = d_in[17];

  int* flag = (int*)d_ws;
  ushort_t* base = (ushort_t*)((char*)d_ws + 64);
  ushort_t* qB   = base;                 // 768*192
  ushort_t* kB   = qB   + 147456;        // 768*192
  ushort_t* vTB  = kB   + 147456;        // [192][768]
  ushort_t* qpB  = vTB  + 147456;        // 768*144
  ushort_t* kpB  = qpB  + 110592;        // 768*144
  ushort_t* vpTB = kpB  + 110592;        // [288][768]  (total 1.77 MB + 64 B)

  k_detect<<<dim3(1), dim3(64), 0, stream>>>(s, flag);
  k_proj<<<dim3(768), dim3(256), 0, stream>>>(flag, s, R, t, Wq, bq, Wkv, bkv,
                                              Wqp, bqp, Wkvp, bkvp,
                                              qB, kB, vTB, qpB, kpB, vpTB);
  k_attn<<<dim3(768), dim3(256), 0, stream>>>(flag, z, R, t, mask, Wb, bb, hw,
                                              qB, kB, vTB, qpB, kpB, vpTB);
  k_out<<<dim3(12, 24), dim3(256), 0, stream>>>(flag, z, Wout, bout, d_out);
}

// Round 4
// 905.911 us; speedup vs baseline: 1.2705x; 1.0786x over previous
//
#include <hip/hip_runtime.h>

// StructureModule (IPA), B=1, N=768. Harness dtype ambiguous (bf16 vs fp32):
// a detect kernel sniffs s[] bit patterns and all kernels branch on the flag.
// dims: C_S=384, C_Z=128, C_H=16, H=12, PQ=4, PV=8, CO=2112
// rocprof r0: FETCH ~305MB = one fp32 z pass -> runtime dtype is fp32.
// rocprof r1 LESSON: fusing 3 far-apart kk-rows/thread ballooned the live
// cacheline set -> 4.5 z-passes from HBM. Consume each 64B line immediately.
// rocprof r2 LESSON: inline z@Wb in attn phase A caps at ~1 TB/s (latency-
// bound: 1-line-deep prefetch + LDS broadcasts on the load critical path).
// -> z@Wb moved to dedicated k_bias kernel (2 rows/lane, depth-2 prefetch);
// attn reads precomputed bT. WRITE_SIZE ~250MB in r1/r2 = harness z-restore
// dirty-line drain, not kernel stores.
// r3: bench infra failed twice (container), no counters -- resubmitting
// the same kernel unchanged.

typedef unsigned short ushort_t;

__device__ __forceinline__ float bfr(ushort_t u) {
  return __uint_as_float(((unsigned int)u) << 16);
}
__device__ __forceinline__ ushort_t f2bf(float f) {
  unsigned int u = __float_as_uint(f);
  u += 0x7FFFu + ((u >> 16) & 1u);
  return (ushort_t)(u >> 16);
}

template<bool BF16>
__device__ __forceinline__ float ld(const void* p, size_t i) {
  if constexpr (BF16) return bfr(((const ushort_t*)p)[i]);
  else                return ((const float*)p)[i];
}
template<bool BF16>
__device__ __forceinline__ void ld4(const void* p, size_t i, float* o) {
  if constexpr (BF16) {
    uint2 u = *(const uint2*)((const ushort_t*)p + i);   // i multiple of 4
    o[0]=__uint_as_float(u.x<<16); o[1]=__uint_as_float(u.x & 0xffff0000u);
    o[2]=__uint_as_float(u.y<<16); o[3]=__uint_as_float(u.y & 0xffff0000u);
  } else {
    float4 v = *(const float4*)((const float*)p + i);
    o[0]=v.x; o[1]=v.y; o[2]=v.z; o[3]=v.w;
  }
}
template<bool BF16>
__device__ __forceinline__ void ld2(const void* p, size_t i, float& x, float& y) {
  if constexpr (BF16) {
    unsigned int u = *(const unsigned int*)((const ushort_t*)p + i);  // i even
    x = __uint_as_float(u << 16); y = __uint_as_float(u & 0xffff0000u);
  } else {
    float2 v = *(const float2*)((const float*)p + i);
    x = v.x; y = v.y;
  }
}
__device__ __forceinline__ void unp8(uint4 v, float* f) {
  f[0]=__uint_as_float(v.x<<16); f[1]=__uint_as_float(v.x&0xffff0000u);
  f[2]=__uint_as_float(v.y<<16); f[3]=__uint_as_float(v.y&0xffff0000u);
  f[4]=__uint_as_float(v.z<<16); f[5]=__uint_as_float(v.z&0xffff0000u);
  f[6]=__uint_as_float(v.w<<16); f[7]=__uint_as_float(v.w&0xffff0000u);
}
__device__ __forceinline__ void unp4(uint2 v, float* f) {
  f[0]=__uint_as_float(v.x<<16); f[1]=__uint_as_float(v.x&0xffff0000u);
  f[2]=__uint_as_float(v.y<<16); f[3]=__uint_as_float(v.y&0xffff0000u);
}
// 16 consecutive floats (one 64B line fp32 / 32B bf16), fully consumed by caller
template<bool BF16>
__device__ __forceinline__ void ld16(const void* p, size_t i, float* o) {
  if constexpr (BF16) {
    const uint4* q = (const uint4*)((const ushort_t*)p + i);
    unp8(q[0], o); unp8(q[1], o+8);
  } else {
    const float4* q = (const float4*)((const float*)p + i);
    *(float4*)&o[0]=q[0]; *(float4*)&o[4]=q[1];
    *(float4*)&o[8]=q[2]; *(float4*)&o[12]=q[3];
  }
}
__device__ __forceinline__ float f4get(float4 v, int e) {   // e compile-time after unroll
  return e==0 ? v.x : (e==1 ? v.y : (e==2 ? v.z : v.w));
}

#define NT 768
#define ZROWE 98304   /* elements per z q-row: 768*128 */
#define NROWS 589824  /* 768*768 z sub-rows of 128 */

// ---------------------------------------------------------------------------
// dtype sniffer: bf16 pairs -> bits[14:7] of each word are a N(0,1) exponent
// ---------------------------------------------------------------------------
__global__ void k_detect(const void* s, int* flag) {
  if (blockIdx.x == 0 && threadIdx.x == 0) {
    const unsigned int* w = (const unsigned int*)s;
    int cnt = 0;
    for (int i = 0; i < 256; ++i) {
      unsigned int e = (w[i] >> 7) & 0xFFu;
      cnt += (e >= 118u && e <= 131u) ? 1 : 0;
    }
    *flag = (cnt >= 128) ? 1 : 0;
  }
}

// ---------------------------------------------------------------------------
// Kernel 1: projections -> bf16 workspace
//   q  [n][192]           k  [n][h*16+c]      vT [c(192)][n]   (transposed!)
//   qp [n][144]           kp [n][h*12+p*3+i]  vpT[j(288)][n]   (transposed!)
// ---------------------------------------------------------------------------
struct ProjSmem {
  float sl[384];
  float pbuf[576];
  float Rl[9];
  float tl[3];
};

template<bool BF16>
__device__ void proj_body(ProjSmem& sm,
            const void* s, const void* R, const void* t,
            const void* Wq, const void* bq, const void* Wkv, const void* bkv,
            const void* Wqp, const void* bqp, const void* Wkvp, const void* bkvp,
            ushort_t* qo, ushort_t* ko, ushort_t* vTo,
            ushort_t* qpo, ushort_t* kpo, ushort_t* vpTo)
{
  const int n = blockIdx.x, tid = threadIdx.x;
  for (int i = tid; i < 96; i += 256) {
    float f[4]; ld4<BF16>(s, (size_t)n*384 + i*4, f);
    *(float4*)&sm.sl[i*4] = make_float4(f[0],f[1],f[2],f[3]);
  }
  if (tid >= 128 && tid < 137) sm.Rl[tid-128] = ld<BF16>(R, (size_t)n*9 + (tid-128));
  if (tid >= 160 && tid < 163) sm.tl[tid-160] = ld<BF16>(t, (size_t)n*3 + (tid-160));
  __syncthreads();

  for (int g = tid; g < 288; g += 256) {     // 288 quads of 4 output cols
    const void* W; const void* bias; int ldw, cj;
    if (g < 48)       { W=Wq;   bias=bq;   ldw=192; cj=g*4;       }
    else if (g < 144) { W=Wkv;  bias=bkv;  ldw=384; cj=g*4-192;   }
    else if (g < 180) { W=Wqp;  bias=bqp;  ldw=144; cj=g*4-576;   }
    else              { W=Wkvp; bias=bkvp; ldw=432; cj=g*4-720;   }
    float a0 = ld<BF16>(bias, cj+0), a1 = ld<BF16>(bias, cj+1),
          a2 = ld<BF16>(bias, cj+2), a3 = ld<BF16>(bias, cj+3);
    #pragma unroll 4
    for (int i = 0; i < 384; ++i) {
      float w[4]; ld4<BF16>(W, (size_t)i*ldw + cj, w);
      const float sv = sm.sl[i];
      a0 = fmaf(sv, w[0], a0); a1 = fmaf(sv, w[1], a1);
      a2 = fmaf(sv, w[2], a2); a3 = fmaf(sv, w[3], a3);
    }
    const int j = g*4;
    if (j < 192) {
      ushort_t* d = qo + (size_t)n*192 + j;
      d[0]=f2bf(a0); d[1]=f2bf(a1); d[2]=f2bf(a2); d[3]=f2bf(a3);
    } else if (j < 576) {
      const int c = j - 192, h = c >> 5, r = c & 31;   // quad stays in one half
      if (r < 16) {
        ushort_t* d = ko + (size_t)n*192 + h*16 + r;
        d[0]=f2bf(a0); d[1]=f2bf(a1); d[2]=f2bf(a2); d[3]=f2bf(a3);
      } else {
        const int cc = h*16 + (r-16);
        vTo[(size_t)(cc+0)*NT + n] = f2bf(a0);
        vTo[(size_t)(cc+1)*NT + n] = f2bf(a1);
        vTo[(size_t)(cc+2)*NT + n] = f2bf(a2);
        vTo[(size_t)(cc+3)*NT + n] = f2bf(a3);
      }
    } else {
      *(float4*)&sm.pbuf[j-576] = make_float4(a0,a1,a2,a3);
    }
  }
  __syncthreads();

  if (tid < 48) {   // q points: j -> (h=j/4, pq=j%4); store [n][j*3+i]
    const int j = tid;
    float lx = sm.pbuf[j], ly = sm.pbuf[48+j], lz = sm.pbuf[96+j];
    #pragma unroll
    for (int i = 0; i < 3; ++i) {
      float g = sm.Rl[i*3+0]*lx + sm.Rl[i*3+1]*ly + sm.Rl[i*3+2]*lz + sm.tl[i];
      qpo[(size_t)n*144 + j*3 + i] = f2bf(g);
    }
  } else if (tid >= 64 && tid < 208) {  // kv points
    const int j = tid - 64;
    float lx = sm.pbuf[144+j], ly = sm.pbuf[288+j], lz = sm.pbuf[432+j];
    const int h = j / 12, pp = j % 12;
    #pragma unroll
    for (int i = 0; i < 3; ++i) {
      float g = sm.Rl[i*3+0]*lx + sm.Rl[i*3+1]*ly + sm.Rl[i*3+2]*lz + sm.tl[i];
      if (pp < 4) kpo[(size_t)n*144 + h*12 + pp*3 + i]         = f2bf(g);
      else        vpTo[(size_t)(h*24 + (pp-4)*3 + i)*NT + n]   = f2bf(g);
    }
  }
}

__global__ __launch_bounds__(256)
void k_proj(const int* flag,
            const void* s, const void* R, const void* t,
            const void* Wq, const void* bq, const void* Wkv, const void* bkv,
            const void* Wqp, const void* bqp, const void* Wkvp, const void* bkvp,
            ushort_t* qo, ushort_t* ko, ushort_t* vTo,
            ushort_t* qpo, ushort_t* kpo, ushort_t* vpTo)
{
  __shared__ ProjSmem sm;
  if (*flag) proj_body<true >(sm, s,R,t,Wq,bq,Wkv,bkv,Wqp,bqp,Wkvp,bkvp,qo,ko,vTo,qpo,kpo,vpTo);
  else       proj_body<false>(sm, s,R,t,Wq,bq,Wkv,bkv,Wqp,bqp,Wkvp,bkvp,qo,ko,vTo,qpo,kpo,vpTo);
}

// ---------------------------------------------------------------------------
// Kernel 1b: bT[h][q*768+k] = (z @ Wb)  -- pure streaming GEMV over z.
// Each thread: 2 CONSECUTIVE rows, depth-2 line-pair prefetch (2 lines/lane
// in flight), Wb broadcast from LDS amortized over both rows. Nothing else
// in the kernel -> the z stream owns the CU.
// ---------------------------------------------------------------------------
struct BiasSmem { float Wbl[128*12]; };   // [c][h], float4-readable

template<bool BF16>
__device__ void bias_body(BiasSmem& sm, const void* z, const void* Wb, float* bT)
{
  const int tid = threadIdx.x;
  for (int i = tid; i < 128*12; i += 256) sm.Wbl[i] = ld<BF16>(Wb, i);
  __syncthreads();

  const int row0 = blockIdx.x*512 + tid*2;          // rows row0, row0+1
  const size_t zb0 = (size_t)row0*128, zb1 = zb0 + 128;
  float acc0[12], acc1[12];
  #pragma unroll
  for (int h = 0; h < 12; ++h) { acc0[h] = 0.f; acc1[h] = 0.f; }

  float A0[16], A1[16], B0[16], B1[16];
  ld16<BF16>(z, zb0, A0);
  ld16<BF16>(z, zb1, B0);
  const float4* Wb4 = (const float4*)sm.Wbl;
  #pragma unroll
  for (int c16 = 0; c16 < 8; ++c16) {
    float* curA = (c16 & 1) ? A1 : A0;  float* nxtA = (c16 & 1) ? A0 : A1;
    float* curB = (c16 & 1) ? B1 : B0;  float* nxtB = (c16 & 1) ? B0 : B1;
    if (c16 < 7) {
      ld16<BF16>(z, zb0 + (size_t)(c16+1)*16, nxtA);
      ld16<BF16>(z, zb1 + (size_t)(c16+1)*16, nxtB);
    }
    #pragma unroll
    for (int e = 0; e < 16; ++e) {
      const int c = c16*16 + e;
      float wr[12];
      *(float4*)&wr[0] = Wb4[c*3+0];
      *(float4*)&wr[4] = Wb4[c*3+1];
      *(float4*)&wr[8] = Wb4[c*3+2];
      const float za = curA[e], zb = curB[e];
      #pragma unroll
      for (int h = 0; h < 12; ++h) {
        acc0[h] = fmaf(za, wr[h], acc0[h]);
        acc1[h] = fmaf(zb, wr[h], acc1[h]);
      }
    }
  }
  #pragma unroll
  for (int h = 0; h < 12; ++h)
    *(float2*)(bT + (size_t)h*NROWS + row0) = make_float2(acc0[h], acc1[h]);
}

__global__ __launch_bounds__(256, 3)
void k_bias(const int* flag, const void* z, const void* Wb, float* bT) {
  __shared__ BiasSmem sm;
  if (*flag) bias_body<true >(sm, z, Wb, bT);
  else       bias_body<false>(sm, z, Wb, bT);
}

// ---------------------------------------------------------------------------
// Kernel 2 (primary): per-query-row attention with precomputed bT.
// LDS 39.6KB -> 4 blocks/CU, grid 768 fully resident. catrow written
// directly to global z row (barrier after C1 z-reads protects the overlay).
// ---------------------------------------------------------------------------
struct __align__(16) AttnSmemB {
  float probs[12 * NT];            // 36864 B
  float opt[288];                  // 1152 B
  float4 ql4[12*4];                // 768 B
  float4 qpl4[12*4];               // 768 B
  float  hwc[12], bbl[12];         // 96 B
};  // 39648 B -> 4 blocks/CU

template<bool BF16>
__device__ void attn_b_body(AttnSmemB& sm,
            void* z, const void* Rg, const void* tg, const void* mg,
            const void* bbp, const void* hwg, const float* bT,
            const ushort_t* qB, const ushort_t* kB, const ushort_t* vTB,
            const ushort_t* qpB, const ushort_t* kpB, const ushort_t* vpTB)
{
  const int qrow = blockIdx.x, tid = threadIdx.x;

  if (tid < 48) {                       // q: 12h x 16, as float4s
    const int h = tid >> 2, part = tid & 3;
    float f[4];
    unp4(*(const uint2*)(qB + (size_t)qrow*192 + h*16 + part*4), f);
    sm.ql4[h*4+part] = make_float4(f[0],f[1],f[2],f[3]);
  } else if (tid >= 64 && tid < 112) {  // qp: 12h x 12 -> padded [h][16]
    const int j = tid - 64, h = j >> 2, part = j & 3;
    if (part < 3) {
      float f[4];
      unp4(*(const uint2*)(qpB + (size_t)qrow*144 + h*12 + part*4), f);
      sm.qpl4[h*4+part] = make_float4(f[0],f[1],f[2],f[3]);
    }
  } else if (tid >= 192 && tid < 204) {
    const int h = tid - 192;
    float x = ld<BF16>(hwg, h);
    float sp = (x > 20.f) ? x : log1pf(expf(x));     // softplus
    sm.hwc[h] = -0.5f * sp * 0.13608276348795434f;   // * sqrt(1/54), fold -0.5
    sm.bbl[h] = ld<BF16>(bbp, h);
  }
  __syncthreads();
  const float mq = ld<BF16>(mg, qrow);

  // ---- Phase A: logits from precomputed bT + K/Kp (no z traffic) ----
  for (int r = 0; r < 3; ++r) {
    const int kk = tid + r*256;
    const size_t bidx = (size_t)qrow*NT + kk;
    float bv[12];
    #pragma unroll
    for (int h = 0; h < 12; ++h) bv[h] = bT[(size_t)h*NROWS + bidx];
    const uint4* kr  = (const uint4*)(kB  + (size_t)kk*192);  // 16B-aligned
    const uint2* kpr = (const uint2*)(kpB + (size_t)kk*144);  // 8B-aligned
    const float mk = ld<BF16>(mg, kk);
    const float maskterm = 100000.0f * (mq*mk - 1.0f);
    #pragma unroll
    for (int h = 0; h < 12; ++h) {
      float kf[16];
      unp8(kr[2*h+0], kf); unp8(kr[2*h+1], kf+8);
      float qf[16];
      *(float4*)&qf[0]  = sm.ql4[h*4+0];
      *(float4*)&qf[4]  = sm.ql4[h*4+1];
      *(float4*)&qf[8]  = sm.ql4[h*4+2];
      *(float4*)&qf[12] = sm.ql4[h*4+3];
      float dot = 0.f;
      #pragma unroll
      for (int j = 0; j < 16; ++j) dot = fmaf(qf[j], kf[j], dot);
      float kpf[12];
      unp4(kpr[3*h+0], kpf); unp4(kpr[3*h+1], kpf+4); unp4(kpr[3*h+2], kpf+8);
      float qpf[12];
      *(float4*)&qpf[0] = sm.qpl4[h*4+0];
      *(float4*)&qpf[4] = sm.qpl4[h*4+1];
      *(float4*)&qpf[8] = sm.qpl4[h*4+2];
      float pts = 0.f;
      #pragma unroll
      for (int p = 0; p < 4; ++p) {
        float dx = qpf[p*3+0]-kpf[p*3+0];
        float dy = qpf[p*3+1]-kpf[p*3+1];
        float dz = qpf[p*3+2]-kpf[p*3+2];
        pts += dx*dx + dy*dy + dz*dz;
      }
      sm.probs[h*NT + kk] = dot * 0.14433756729740643f
                          + (bv[h] + sm.bbl[h]) * 0.57735026918962576f
                          + sm.hwc[h] * pts + maskterm;
    }
  }
  __syncthreads();

  // ---- Phase B: softmax (wave w -> heads w, w+4, w+8), float4 accesses ----
  {
    const int wave = tid >> 6, lane = tid & 63;
    #pragma unroll
    for (int hh = 0; hh < 3; ++hh) {
      const int h = wave + hh*4;
      float4* P4 = (float4*)sm.probs + h*192;
      float4 v0 = P4[lane], v1 = P4[64+lane], v2 = P4[128+lane];
      float m = fmaxf(fmaxf(fmaxf(v0.x,v0.y),fmaxf(v0.z,v0.w)),
                fmaxf(fmaxf(fmaxf(v1.x,v1.y),fmaxf(v1.z,v1.w)),
                      fmaxf(fmaxf(v2.x,v2.y),fmaxf(v2.z,v2.w))));
      #pragma unroll
      for (int off = 32; off; off >>= 1) m = fmaxf(m, __shfl_xor(m, off, 64));
      v0.x=__expf(v0.x-m); v0.y=__expf(v0.y-m); v0.z=__expf(v0.z-m); v0.w=__expf(v0.w-m);
      v1.x=__expf(v1.x-m); v1.y=__expf(v1.y-m); v1.z=__expf(v1.z-m); v1.w=__expf(v1.w-m);
      v2.x=__expf(v2.x-m); v2.y=__expf(v2.y-m); v2.z=__expf(v2.z-m); v2.w=__expf(v2.w-m);
      float ssum = (v0.x+v0.y+v0.z+v0.w) + (v1.x+v1.y+v1.z+v1.w) + (v2.x+v2.y+v2.z+v2.w);
      #pragma unroll
      for (int off = 32; off; off >>= 1) ssum += __shfl_xor(ssum, off, 64);
      const float inv = 1.0f / ssum;
      v0.x*=inv; v0.y*=inv; v0.z*=inv; v0.w*=inv;
      v1.x*=inv; v1.y*=inv; v1.z*=inv; v1.w*=inv;
      v2.x*=inv; v2.y*=inv; v2.z*=inv; v2.w*=inv;
      P4[lane]=v0; P4[64+lane]=v1; P4[128+lane]=v2;
    }
  }
  __syncthreads();

  float* crow;
  if constexpr (BF16) crow = (float*)((ushort_t*)z + (size_t)qrow*ZROWE);
  else                crow = (float*)z + (size_t)qrow*ZROWE;

  // ---- Phase C1: o_pair (only z pass in this kernel). Wave covers a full
  // 512B z row per instruction. Results written DIRECTLY to crow after the
  // barrier (all block z-reads complete -> overlay-scribble is safe).
  {
    const int c2 = (tid & 63) * 2;
    const int h0 = (tid >> 6) * 3;
    const float4* p0 = (const float4*)(sm.probs + (h0+0)*NT);
    const float4* p1 = (const float4*)(sm.probs + (h0+1)*NT);
    const float4* p2 = (const float4*)(sm.probs + (h0+2)*NT);
    const size_t zrb = (size_t)qrow*ZROWE;
    float a00=0.f,a01=0.f,a10=0.f,a11=0.f,a20=0.f,a21=0.f;
    #pragma unroll 2
    for (int tt = 0; tt < 192; ++tt) {
      float4 pa = p0[tt], pb = p1[tt], pc = p2[tt];
      #pragma unroll
      for (int e = 0; e < 4; ++e) {
        float zx, zy;
        ld2<BF16>(z, zrb + (size_t)(tt*4+e)*128 + c2, zx, zy);
        const float w0 = f4get(pa,e), w1 = f4get(pb,e), w2 = f4get(pc,e);
        a00 = fmaf(w0, zx, a00); a01 = fmaf(w0, zy, a01);
        a10 = fmaf(w1, zx, a10); a11 = fmaf(w1, zy, a11);
        a20 = fmaf(w2, zx, a20); a21 = fmaf(w2, zy, a21);
      }
    }
    __syncthreads();   // ALL z reads in block done before scribbling z row
    *(float2*)(crow + 576 + (h0+0)*128 + c2) = make_float2(a00, a01);
    *(float2*)(crow + 576 + (h0+1)*128 + c2) = make_float2(a10, a11);
    *(float2*)(crow + 576 + (h0+2)*128 + c2) = make_float2(a20, a21);
  }

  // ---- Phase C2: o (192) and o_pt global-frame sums (288), transposed
  // bf16 workspace -> uint4 streaming loads, probs as b128 broadcast ----
  for (int idx = tid; idx < 480; idx += 256) {
    const ushort_t* src; int h;
    if (idx < 192) { h = idx >> 4;            src = vTB  + (size_t)idx*NT; }
    else           { const int j = idx - 192; h = j/24;  src = vpTB + (size_t)j*NT; }
    const uint4*  s4 = (const uint4*)src;
    const float4* pr = (const float4*)(sm.probs + h*NT);
    float acc = 0.f;
    #pragma unroll 2
    for (int tt = 0; tt < 96; ++tt) {
      float vf[8]; unp8(s4[tt], vf);
      float4 pa = pr[2*tt], pb = pr[2*tt+1];
      acc = fmaf(pa.x, vf[0], acc); acc = fmaf(pa.y, vf[1], acc);
      acc = fmaf(pa.z, vf[2], acc); acc = fmaf(pa.w, vf[3], acc);
      acc = fmaf(pb.x, vf[4], acc); acc = fmaf(pb.y, vf[5], acc);
      acc = fmaf(pb.z, vf[6], acc); acc = fmaf(pb.w, vf[7], acc);
    }
    if (idx < 192) crow[idx] = acc;       // direct global store
    else           sm.opt[idx-192] = acc; // needed cross-thread in phase D
  }
  __syncthreads();

  // ---- Phase D: inverse rigid, norms; direct global stores ----
  if (tid < 96) {
    const int h = tid >> 3, p = tid & 7;
    const int j = h*24 + p*3;
    float gx = sm.opt[j], gy = sm.opt[j+1], gz = sm.opt[j+2];
    gx -= ld<BF16>(tg, qrow*3+0); gy -= ld<BF16>(tg, qrow*3+1); gz -= ld<BF16>(tg, qrow*3+2);
    float r[9];
    #pragma unroll
    for (int i = 0; i < 9; ++i) r[i] = ld<BF16>(Rg, qrow*9 + i);
    float lx = r[0]*gx + r[3]*gy + r[6]*gz;   // R^T * g
    float ly = r[1]*gx + r[4]*gy + r[7]*gz;
    float lz = r[2]*gx + r[5]*gy + r[8]*gz;
    float nrm = sqrtf(lx*lx + ly*ly + lz*lz + 1e-8f);
    const int jj = h*8 + p;
    crow[192 + jj] = lx;
    crow[288 + jj] = ly;
    crow[384 + jj] = lz;
    crow[480 + jj] = nrm;
  }
}

__global__ __launch_bounds__(256, 4)
void k_attn_b(const int* flag,
            void* z, const void* Rg, const void* tg, const void* mg,
            const void* bbp, const void* hwg, const float* bT,
            const ushort_t* qB, const ushort_t* kB, const ushort_t* vTB,
            const ushort_t* qpB, const ushort_t* kpB, const ushort_t* vpTB)
{
  __shared__ AttnSmemB sm;
  if (*flag) attn_b_body<true >(sm, z,Rg,tg,mg,bbp,hwg,bT,qB,kB,vTB,qpB,kpB,vpTB);
  else       attn_b_body<false>(sm, z,Rg,tg,mg,bbp,hwg,bT,qB,kB,vTB,qpB,kpB,vpTB);
}

// ---------------------------------------------------------------------------
// Kernel 2 (fallback, ws too small for bT): exact round-2 kernel.
// ---------------------------------------------------------------------------
struct __align__(16) AttnSmemF {
  float probs[12 * NT];
  union {
    struct {
      float4 Wbl[128*3];
      float4 ql4[12*4];
      float4 qpl4[12*4];
      float  hwc[12], bbl[12];
    } a;
    struct {
      float catrow[2112];
      float opt[288];
    } c;
  } u;
};

template<bool BF16>
__device__ void attn_f_body(AttnSmemF& sm,
            void* z, const void* Rg, const void* tg, const void* mg,
            const void* Wb, const void* bbp, const void* hwg,
            const ushort_t* qB, const ushort_t* kB, const ushort_t* vTB,
            const ushort_t* qpB, const ushort_t* kpB, const ushort_t* vpTB)
{
  const int qrow = blockIdx.x, tid = threadIdx.x;

  for (int i = tid; i < 128*12; i += 256) ((float*)sm.u.a.Wbl)[i] = ld<BF16>(Wb, i);
  if (tid < 48) {
    const int h = tid >> 2, part = tid & 3;
    float f[4];
    unp4(*(const uint2*)(qB + (size_t)qrow*192 + h*16 + part*4), f);
    sm.u.a.ql4[h*4+part] = make_float4(f[0],f[1],f[2],f[3]);
  } else if (tid >= 64 && tid < 112) {
    const int j = tid - 64, h = j >> 2, part = j & 3;
    if (part < 3) {
      float f[4];
      unp4(*(const uint2*)(qpB + (size_t)qrow*144 + h*12 + part*4), f);
      sm.u.a.qpl4[h*4+part] = make_float4(f[0],f[1],f[2],f[3]);
    }
  } else if (tid >= 192 && tid < 204) {
    const int h = tid - 192;
    float x = ld<BF16>(hwg, h);
    float sp = (x > 20.f) ? x : log1pf(expf(x));
    sm.u.a.hwc[h] = -0.5f * sp * 0.13608276348795434f;
    sm.u.a.bbl[h] = ld<BF16>(bbp, h);
  }
  __syncthreads();
  const float mq = ld<BF16>(mg, qrow);

  {
    const float4* Wb4 = sm.u.a.Wbl;
    for (int r = 0; r < 3; ++r) {
      const int kk = tid + r*256;
      float accb[12];
      #pragma unroll
      for (int h = 0; h < 12; ++h) accb[h] = sm.u.a.bbl[h];
      const size_t zb = ((size_t)qrow*NT + kk)*128;
      float zb0[16], zb1[16];
      ld16<BF16>(z, zb, zb0);
      #pragma unroll
      for (int c16 = 0; c16 < 8; ++c16) {
        float* cur = (c16 & 1) ? zb1 : zb0;
        float* nxt = (c16 & 1) ? zb0 : zb1;
        if (c16 < 7) ld16<BF16>(z, zb + (size_t)(c16+1)*16, nxt);
        #pragma unroll
        for (int e = 0; e < 16; ++e) {
          const int c = c16*16 + e;
          float wr[12];
          *(float4*)&wr[0] = Wb4[c*3+0];
          *(float4*)&wr[4] = Wb4[c*3+1];
          *(float4*)&wr[8] = Wb4[c*3+2];
          const float zc = cur[e];
          #pragma unroll
          for (int h = 0; h < 12; ++h) accb[h] = fmaf(zc, wr[h], accb[h]);
        }
      }
      const uint4* kr  = (const uint4*)(kB  + (size_t)kk*192);
      const uint2* kpr = (const uint2*)(kpB + (size_t)kk*144);
      const float mk = ld<BF16>(mg, kk);
      const float maskterm = 100000.0f * (mq*mk - 1.0f);
      #pragma unroll
      for (int h = 0; h < 12; ++h) {
        float kf[16];
        unp8(kr[2*h+0], kf); unp8(kr[2*h+1], kf+8);
        float qf[16];
        *(float4*)&qf[0]  = sm.u.a.ql4[h*4+0];
        *(float4*)&qf[4]  = sm.u.a.ql4[h*4+1];
        *(float4*)&qf[8]  = sm.u.a.ql4[h*4+2];
        *(float4*)&qf[12] = sm.u.a.ql4[h*4+3];
        float dot = 0.f;
        #pragma unroll
        for (int j = 0; j < 16; ++j) dot = fmaf(qf[j], kf[j], dot);
        float kpf[12];
        unp4(kpr[3*h+0], kpf); unp4(kpr[3*h+1], kpf+4); unp4(kpr[3*h+2], kpf+8);
        float qpf[12];
        *(float4*)&qpf[0] = sm.u.a.qpl4[h*4+0];
        *(float4*)&qpf[4] = sm.u.a.qpl4[h*4+1];
        *(float4*)&qpf[8] = sm.u.a.qpl4[h*4+2];
        float pts = 0.f;
        #pragma unroll
        for (int p = 0; p < 4; ++p) {
          float dx = qpf[p*3+0]-kpf[p*3+0];
          float dy = qpf[p*3+1]-kpf[p*3+1];
          float dz = qpf[p*3+2]-kpf[p*3+2];
          pts += dx*dx + dy*dy + dz*dz;
        }
        sm.probs[h*NT + kk] = dot * 0.14433756729740643f
                            + accb[h] * 0.57735026918962576f
                            + sm.u.a.hwc[h] * pts + maskterm;
      }
    }
  }
  __syncthreads();

  {
    const int wave = tid >> 6, lane = tid & 63;
    #pragma unroll
    for (int hh = 0; hh < 3; ++hh) {
      const int h = wave + hh*4;
      float4* P4 = (float4*)sm.probs + h*192;
      float4 v0 = P4[lane], v1 = P4[64+lane], v2 = P4[128+lane];
      float m = fmaxf(fmaxf(fmaxf(v0.x,v0.y),fmaxf(v0.z,v0.w)),
                fmaxf(fmaxf(fmaxf(v1.x,v1.y),fmaxf(v1.z,v1.w)),
                      fmaxf(fmaxf(v2.x,v2.y),fmaxf(v2.z,v2.w))));
      #pragma unroll
      for (int off = 32; off; off >>= 1) m = fmaxf(m, __shfl_xor(m, off, 64));
      v0.x=__expf(v0.x-m); v0.y=__expf(v0.y-m); v0.z=__expf(v0.z-m); v0.w=__expf(v0.w-m);
      v1.x=__expf(v1.x-m); v1.y=__expf(v1.y-m); v1.z=__expf(v1.z-m); v1.w=__expf(v1.w-m);
      v2.x=__expf(v2.x-m); v2.y=__expf(v2.y-m); v2.z=__expf(v2.z-m); v2.w=__expf(v2.w-m);
      float ssum = (v0.x+v0.y+v0.z+v0.w) + (v1.x+v1.y+v1.z+v1.w) + (v2.x+v2.y+v2.z+v2.w);
      #pragma unroll
      for (int off = 32; off; off >>= 1) ssum += __shfl_xor(ssum, off, 64);
      const float inv = 1.0f / ssum;
      v0.x*=inv; v0.y*=inv; v0.z*=inv; v0.w*=inv;
      v1.x*=inv; v1.y*=inv; v1.z*=inv; v1.w*=inv;
      v2.x*=inv; v2.y*=inv; v2.z*=inv; v2.w*=inv;
      P4[lane]=v0; P4[64+lane]=v1; P4[128+lane]=v2;
    }
  }
  __syncthreads();

  {
    const int c2 = (tid & 63) * 2;
    const int h0 = (tid >> 6) * 3;
    const float4* p0 = (const float4*)(sm.probs + (h0+0)*NT);
    const float4* p1 = (const float4*)(sm.probs + (h0+1)*NT);
    const float4* p2 = (const float4*)(sm.probs + (h0+2)*NT);
    const size_t zrb = (size_t)qrow*ZROWE;
    float a00=0.f,a01=0.f,a10=0.f,a11=0.f,a20=0.f,a21=0.f;
    #pragma unroll 2
    for (int tt = 0; tt < 192; ++tt) {
      float4 pa = p0[tt], pb = p1[tt], pc = p2[tt];
      #pragma unroll
      for (int e = 0; e < 4; ++e) {
        float zx, zy;
        ld2<BF16>(z, zrb + (size_t)(tt*4+e)*128 + c2, zx, zy);
        const float w0 = f4get(pa,e), w1 = f4get(pb,e), w2 = f4get(pc,e);
        a00 = fmaf(w0, zx, a00); a01 = fmaf(w0, zy, a01);
        a10 = fmaf(w1, zx, a10); a11 = fmaf(w1, zy, a11);
        a20 = fmaf(w2, zx, a20); a21 = fmaf(w2, zy, a21);
      }
    }
    sm.u.c.catrow[576 + (h0+0)*128 + c2]   = a00;
    sm.u.c.catrow[576 + (h0+0)*128 + c2+1] = a01;
    sm.u.c.catrow[576 + (h0+1)*128 + c2]   = a10;
    sm.u.c.catrow[576 + (h0+1)*128 + c2+1] = a11;
    sm.u.c.catrow[576 + (h0+2)*128 + c2]   = a20;
    sm.u.c.catrow[576 + (h0+2)*128 + c2+1] = a21;
  }

  for (int idx = tid; idx < 480; idx += 256) {
    const ushort_t* src; int h;
    if (idx < 192) { h = idx >> 4;            src = vTB  + (size_t)idx*NT; }
    else           { const int j = idx - 192; h = j/24;  src = vpTB + (size_t)j*NT; }
    const uint4*  s4 = (const uint4*)src;
    const float4* pr = (const float4*)(sm.probs + h*NT);
    float acc = 0.f;
    #pragma unroll 2
    for (int tt = 0; tt < 96; ++tt) {
      float vf[8]; unp8(s4[tt], vf);
      float4 pa = pr[2*tt], pb = pr[2*tt+1];
      acc = fmaf(pa.x, vf[0], acc); acc = fmaf(pa.y, vf[1], acc);
      acc = fmaf(pa.z, vf[2], acc); acc = fmaf(pa.w, vf[3], acc);
      acc = fmaf(pb.x, vf[4], acc); acc = fmaf(pb.y, vf[5], acc);
      acc = fmaf(pb.z, vf[6], acc); acc = fmaf(pb.w, vf[7], acc);
    }
    if (idx < 192) sm.u.c.catrow[idx]   = acc;
    else           sm.u.c.opt[idx-192]  = acc;
  }
  __syncthreads();

  if (tid < 96) {
    const int h = tid >> 3, p = tid & 7;
    const int j = h*24 + p*3;
    float gx = sm.u.c.opt[j], gy = sm.u.c.opt[j+1], gz = sm.u.c.opt[j+2];
    gx -= ld<BF16>(tg, qrow*3+0); gy -= ld<BF16>(tg, qrow*3+1); gz -= ld<BF16>(tg, qrow*3+2);
    float r[9];
    #pragma unroll
    for (int i = 0; i < 9; ++i) r[i] = ld<BF16>(Rg, qrow*9 + i);
    float lx = r[0]*gx + r[3]*gy + r[6]*gz;
    float ly = r[1]*gx + r[4]*gy + r[7]*gz;
    float lz = r[2]*gx + r[5]*gy + r[8]*gz;
    float nrm = sqrtf(lx*lx + ly*ly + lz*lz + 1e-8f);
    const int jj = h*8 + p;
    sm.u.c.catrow[192 + jj] = lx;
    sm.u.c.catrow[288 + jj] = ly;
    sm.u.c.catrow[384 + jj] = lz;
    sm.u.c.catrow[480 + jj] = nrm;
  }
  __syncthreads();

  {
    float* crow;
    if constexpr (BF16) crow = (float*)((ushort_t*)z + (size_t)qrow*ZROWE);
    else                crow = (float*)z + (size_t)qrow*ZROWE;
    float4* c4p = (float4*)crow;
    const float4* src4 = (const float4*)sm.u.c.catrow;
    for (int i = tid; i < 528; i += 256) c4p[i] = src4[i];
  }
}

__global__ __launch_bounds__(256, 3)
void k_attn_f(const int* flag,
            void* z, const void* Rg, const void* tg, const void* mg,
            const void* Wb, const void* bbp, const void* hwg,
            const ushort_t* qB, const ushort_t* kB, const ushort_t* vTB,
            const ushort_t* qpB, const ushort_t* kpB, const ushort_t* vpTB)
{
  __shared__ AttnSmemF sm;
  if (*flag) attn_f_body<true >(sm, z,Rg,tg,mg,Wb,bbp,hwg,qB,kB,vTB,qpB,kpB,vpTB);
  else       attn_f_body<false>(sm, z,Rg,tg,mg,Wb,bbp,hwg,qB,kB,vTB,qpB,kpB,vpTB);
}

// ---------------------------------------------------------------------------
// Kernel 3: out = cat(768x2112, strided in z) @ Wout(2112x384) + bout
// ---------------------------------------------------------------------------
struct OutSmem { float As[32][33]; float Bs[32][33]; };

template<bool BF16>
__device__ void out_body(OutSmem& sm, const void* zcat, const void* Wout,
                         const void* bout, void* out)
{
  const size_t RS = BF16 ? 49152 : 98304;   // float stride of cat rows in z
  const float* cat = (const float*)zcat;
  const int n0 = blockIdx.x * 32, m0 = blockIdx.y * 32, tid = threadIdx.x;
  const int tm = (tid >> 4) * 2, tn = (tid & 15) * 2;
  float acc00 = 0.f, acc01 = 0.f, acc10 = 0.f, acc11 = 0.f;
  const int e = tid * 4;
  const int lm = e >> 5, lk = e & 31;
  for (int k0 = 0; k0 < 2112; k0 += 32) {
    float4 a = *(const float4*)(cat + (size_t)(m0 + lm)*RS + k0 + lk);
    sm.As[lk+0][lm] = a.x; sm.As[lk+1][lm] = a.y; sm.As[lk+2][lm] = a.z; sm.As[lk+3][lm] = a.w;
    float bw[4];
    ld4<BF16>(Wout, (size_t)(k0 + lm)*384 + n0 + lk, bw);
    sm.Bs[lm][lk+0] = bw[0]; sm.Bs[lm][lk+1] = bw[1];
    sm.Bs[lm][lk+2] = bw[2]; sm.Bs[lm][lk+3] = bw[3];
    __syncthreads();
    #pragma unroll
    for (int kk = 0; kk < 32; ++kk) {
      float a0 = sm.As[kk][tm], a1 = sm.As[kk][tm+1];
      float b0 = sm.Bs[kk][tn], b1 = sm.Bs[kk][tn+1];
      acc00 = fmaf(a0,b0,acc00); acc01 = fmaf(a0,b1,acc01);
      acc10 = fmaf(a1,b0,acc10); acc11 = fmaf(a1,b1,acc11);
    }
    __syncthreads();
  }
  float bb0 = ld<BF16>(bout, n0+tn), bb1 = ld<BF16>(bout, n0+tn+1);
  float v00 = acc00+bb0, v01 = acc01+bb1, v10 = acc10+bb0, v11 = acc11+bb1;
  if constexpr (BF16) {
    ushort_t* o = (ushort_t*)out;
    o[(size_t)(m0+tm)*384   + n0+tn]   = f2bf(v00);
    o[(size_t)(m0+tm)*384   + n0+tn+1] = f2bf(v01);
    o[(size_t)(m0+tm+1)*384 + n0+tn]   = f2bf(v10);
    o[(size_t)(m0+tm+1)*384 + n0+tn+1] = f2bf(v11);
  } else {
    float* o = (float*)out;
    o[(size_t)(m0+tm)*384   + n0+tn]   = v00;
    o[(size_t)(m0+tm)*384   + n0+tn+1] = v01;
    o[(size_t)(m0+tm+1)*384 + n0+tn]   = v10;
    o[(size_t)(m0+tm+1)*384 + n0+tn+1] = v11;
  }
}

__global__ __launch_bounds__(256)
void k_out(const int* flag, const void* zcat, const void* Wout,
           const void* bout, void* out)
{
  __shared__ OutSmem sm;
  if (*flag) out_body<true >(sm, zcat, Wout, bout, out);
  else       out_body<false>(sm, zcat, Wout, bout, out);
}

// ---------------------------------------------------------------------------
extern "C" void kernel_launch(void* const* d_in, const int* in_sizes, int n_in,
                              void* d_out, int out_size, void* d_ws, size_t ws_size,
                              hipStream_t stream) {
  const void* s    = d_in[0];
  void*       z    = d_in[1];   // also cat scratch (row-private)
  const void* R    = d_in[2];
  const void* t    = d_in[3];
  const void* mask = d_in[4];
  const void* Wq   = d_in[5];
  const void* bq   = d_in[6];
  const void* Wkv  = d_in[7];
  const void* bkv  = d_in[8];
  const void* Wqp  = d_in[9];
  const void* bqp  = d_in[10];
  const void* Wkvp = d_in[11];
  const void* bkvp = d_in[12];
  const void* Wb   = d_in[13];
  const void* bb   = d_in[14];
  const void* hw   = d_in[15];
  const void* Wout = d_in[16];
  const void* bout = d_in[17];

  int* flag = (int*)d_ws;
  ushort_t* base = (ushort_t*)((char*)d_ws + 64);
  ushort_t* qB   = base;                 // 768*192
  ushort_t* kB   = qB   + 147456;        // 768*192
  ushort_t* vTB  = kB   + 147456;        // [192][768]
  ushort_t* qpB  = vTB  + 147456;        // 768*144
  ushort_t* kpB  = qpB  + 110592;        // 768*144
  ushort_t* vpTB = kpB  + 110592;        // [288][768]  (ws so far: 1769536 B)
  float*    bT   = (float*)((char*)d_ws + 1769536);   // [12][589824] = 28.3 MB

  const bool use_b = ws_size >= (size_t)1769536 + 28311552u;

  k_detect<<<dim3(1), dim3(64), 0, stream>>>(s, flag);
  if (use_b)
    k_bias<<<dim3(1152), dim3(256), 0, stream>>>(flag, z, Wb, bT);
  k_proj<<<dim3(768), dim3(256), 0, stream>>>(flag, s, R, t, Wq, bq, Wkv, bkv,
                                              Wqp, bqp, Wkvp, bkvp,
                                              qB, kB, vTB, qpB, kpB, vpTB);
  if (use_b)
    k_attn_b<<<dim3(768), dim3(256), 0, stream>>>(flag, z, R, t, mask, bb, hw, bT,
                                                  qB, kB, vTB, qpB, kpB, vpTB);
  else
    k_attn_f<<<dim3(768), dim3(256), 0, stream>>>(flag, z, R, t, mask, Wb, bb, hw,
                                                  qB, kB, vTB, qpB, kpB, vpTB);
  k_out<<<dim3(12, 24), dim3(256), 0, stream>>>(flag, z, Wout, bout, d_out);
}